// Round 1
// baseline (711.125 us; speedup 1.0000x reference)
//
#include <hip/hip_runtime.h>
#include <math.h>

#define NN 50000
#define EE 800000
#define EP (EE + NN)          // 850000 edges incl self-loops
#define INF_ 256
#define OF 128
#define NEG_SLOPE 0.2f
#define BN_EPS 1e-5f

__device__ __forceinline__ void atomicMaxF(float* addr, float val) {
    // sign-split trick: works for arbitrary float contents incl. 0xFFFFFFFF sentinel
    if (val >= 0.f) atomicMax((int*)addr, __float_as_int(val));
    else            atomicMin((unsigned int*)addr, __float_as_uint(val));
}

// ---------------- GEMM: h = x @ W, plus a_src/a_dst attention dots ----------------
// block: 256 threads, 32 rows x 128 cols per block.
// thread: rows (tid>>4) and (tid>>4)+16; cols c0..c0+3 and c0+64..c0+67, c0=(tid&15)*4
__global__ __launch_bounds__(256) void k_gemm(
    const float* __restrict__ x, const float* __restrict__ W,
    const float* __restrict__ att_s, const float* __restrict__ att_d,
    float* __restrict__ h, float* __restrict__ a_src, float* __restrict__ a_dst)
{
    __shared__ float xs[32 * 260];   // padded stride 260 (16B-aligned rows, no bank conflict)
    __shared__ float ws[64 * 128];
    const int tid  = threadIdx.x;
    const int row0 = blockIdx.x * 32;

    // stage x tile (clamp rows for the final partial block)
    for (int i = tid; i < 32 * 64; i += 256) {
        int r  = i >> 6;
        int c4 = (i & 63) << 2;
        int rr = row0 + r; if (rr >= NN) rr = NN - 1;
        *(float4*)&xs[r * 260 + c4] = *(const float4*)&x[rr * INF_ + c4];
    }

    const int ra = tid >> 4;            // 0..15
    const int c0 = (tid & 15) << 2;     // 0,4,...,60
    float acc[2][8] = {};

    for (int kc = 0; kc < 4; ++kc) {
        __syncthreads();
        for (int i = tid; i < 64 * 32; i += 256) {
            int kk = i >> 5;
            int c4 = (i & 31) << 2;
            *(float4*)&ws[kk * 128 + c4] = *(const float4*)&W[(kc * 64 + kk) * OF + c4];
        }
        __syncthreads();
        #pragma unroll 8
        for (int kk = 0; kk < 64; ++kk) {
            float4 w0 = *(float4*)&ws[kk * 128 + c0];
            float4 w1 = *(float4*)&ws[kk * 128 + c0 + 64];
            float wv[8] = {w0.x, w0.y, w0.z, w0.w, w1.x, w1.y, w1.z, w1.w};
            float xa = xs[ra * 260 + (kc << 6) + kk];
            float xb = xs[(ra + 16) * 260 + (kc << 6) + kk];
            #pragma unroll
            for (int j = 0; j < 8; ++j) {
                acc[0][j] = fmaf(xa, wv[j], acc[0][j]);
                acc[1][j] = fmaf(xb, wv[j], acc[1][j]);
            }
        }
    }

    // epilogue: write h, compute attention dots, 8-lane shuffle reduce
    float4 As0 = *(const float4*)&att_s[c0];
    float4 As1 = *(const float4*)&att_s[c0 + 64];
    float4 Ad0 = *(const float4*)&att_d[c0];
    float4 Ad1 = *(const float4*)&att_d[c0 + 64];

    #pragma unroll
    for (int rr = 0; rr < 2; ++rr) {
        int row = row0 + ra + rr * 16;
        bool ok = (row < NN);
        if (ok) {
            *(float4*)&h[row * OF + c0]      = make_float4(acc[rr][0], acc[rr][1], acc[rr][2], acc[rr][3]);
            *(float4*)&h[row * OF + c0 + 64] = make_float4(acc[rr][4], acc[rr][5], acc[rr][6], acc[rr][7]);
        }
        float s0 = acc[rr][0]*As0.x + acc[rr][1]*As0.y + acc[rr][2]*As0.z + acc[rr][3]*As0.w;
        float s1 = acc[rr][4]*As1.x + acc[rr][5]*As1.y + acc[rr][6]*As1.z + acc[rr][7]*As1.w;
        float d0 = acc[rr][0]*Ad0.x + acc[rr][1]*Ad0.y + acc[rr][2]*Ad0.z + acc[rr][3]*Ad0.w;
        float d1 = acc[rr][4]*Ad1.x + acc[rr][5]*Ad1.y + acc[rr][6]*Ad1.z + acc[rr][7]*Ad1.w;
        // lanes tid&7 form the reduction group (same row, same head-pair)
        s0 += __shfl_xor(s0, 1); s0 += __shfl_xor(s0, 2); s0 += __shfl_xor(s0, 4);
        s1 += __shfl_xor(s1, 1); s1 += __shfl_xor(s1, 2); s1 += __shfl_xor(s1, 4);
        d0 += __shfl_xor(d0, 1); d0 += __shfl_xor(d0, 2); d0 += __shfl_xor(d0, 4);
        d1 += __shfl_xor(d1, 1); d1 += __shfl_xor(d1, 2); d1 += __shfl_xor(d1, 4);
        if (ok && (tid & 7) == 0) {
            int hh = (tid >> 3) & 1;       // head of first quad: 0 or 1; second quad: +2
            a_src[row * 4 + hh]     = s0;
            a_src[row * 4 + hh + 2] = s1;
            a_dst[row * 4 + hh]     = d0;
            a_dst[row * 4 + hh + 2] = d1;
        }
    }
}

// ---------------- edge pass A: leaky-relu'd logits -> segment max; degree counts ----------------
__global__ __launch_bounds__(256) void k_edge_max(
    const int* __restrict__ ei, const float* __restrict__ a_src,
    const float* __restrict__ a_dst, float* __restrict__ emax, int* __restrict__ counts)
{
    int idx = blockIdx.x * 256 + threadIdx.x;
    if (idx >= EP) return;
    int s, d;
    if (idx < EE) { s = ei[idx]; d = ei[EE + idx]; }
    else          { s = d = idx - EE; }               // self-loop
    float4 as = *(const float4*)&a_src[s * 4];
    float4 ad = *(const float4*)&a_dst[d * 4];
    float e0 = as.x + ad.x; e0 = e0 > 0.f ? e0 : NEG_SLOPE * e0;
    float e1 = as.y + ad.y; e1 = e1 > 0.f ? e1 : NEG_SLOPE * e1;
    float e2 = as.z + ad.z; e2 = e2 > 0.f ? e2 : NEG_SLOPE * e2;
    float e3 = as.w + ad.w; e3 = e3 > 0.f ? e3 : NEG_SLOPE * e3;
    atomicMaxF(&emax[d * 4 + 0], e0);
    atomicMaxF(&emax[d * 4 + 1], e1);
    atomicMaxF(&emax[d * 4 + 2], e2);
    atomicMaxF(&emax[d * 4 + 3], e3);
    atomicAdd(&counts[d], 1);
}

// ---------------- exclusive scan of counts -> row_start / fill_pos (single block) ----------------
__global__ __launch_bounds__(1024) void k_scan(
    const int* __restrict__ counts, int* __restrict__ row_start, int* __restrict__ fill_pos)
{
    __shared__ int part[1024];
    const int tid   = threadIdx.x;
    const int chunk = (NN + 1023) / 1024;  // 49
    int b = tid * chunk;
    int e = b + chunk; if (e > NN) e = NN; if (b > NN) b = NN;
    int s = 0;
    for (int i = b; i < e; ++i) s += counts[i];
    part[tid] = s;
    __syncthreads();
    for (int off = 1; off < 1024; off <<= 1) {
        int v = (tid >= off) ? part[tid - off] : 0;
        __syncthreads();
        part[tid] += v;
        __syncthreads();
    }
    int excl = tid ? part[tid - 1] : 0;
    for (int i = b; i < e; ++i) {
        row_start[i] = excl;
        fill_pos[i]  = excl;
        excl += counts[i];
    }
    if (tid == 1023) row_start[NN] = part[1023];
}

// ---------------- edge pass B: exp(e - max), denom atomics, CSR fill ----------------
__global__ __launch_bounds__(256) void k_edge_exp(
    const int* __restrict__ ei, const float* __restrict__ a_src,
    const float* __restrict__ a_dst, const float* __restrict__ emax,
    float* __restrict__ denom, int* __restrict__ fill_pos,
    int* __restrict__ csr_src, float* __restrict__ csr_exp)
{
    int idx = blockIdx.x * 256 + threadIdx.x;
    if (idx >= EP) return;
    int s, d;
    if (idx < EE) { s = ei[idx]; d = ei[EE + idx]; }
    else          { s = d = idx - EE; }
    float4 as = *(const float4*)&a_src[s * 4];
    float4 ad = *(const float4*)&a_dst[d * 4];
    float4 em = *(const float4*)&emax[d * 4];
    float e0 = as.x + ad.x; e0 = e0 > 0.f ? e0 : NEG_SLOPE * e0;
    float e1 = as.y + ad.y; e1 = e1 > 0.f ? e1 : NEG_SLOPE * e1;
    float e2 = as.z + ad.z; e2 = e2 > 0.f ? e2 : NEG_SLOPE * e2;
    float e3 = as.w + ad.w; e3 = e3 > 0.f ? e3 : NEG_SLOPE * e3;
    float x0 = expf(e0 - em.x);
    float x1 = expf(e1 - em.y);
    float x2 = expf(e2 - em.z);
    float x3 = expf(e3 - em.w);
    atomicAdd(&denom[d * 4 + 0], x0);
    atomicAdd(&denom[d * 4 + 1], x1);
    atomicAdd(&denom[d * 4 + 2], x2);
    atomicAdd(&denom[d * 4 + 3], x3);
    int pos = atomicAdd(&fill_pos[d], 1);
    csr_src[pos] = s;
    *(float4*)&csr_exp[pos * 4] = make_float4(x0, x1, x2, x3);
}

// ---------------- gather: one wave per dst node, lane owns 2 output features ----------------
__global__ __launch_bounds__(256) void k_gather(
    const float* __restrict__ h, const int* __restrict__ csr_src,
    const float* __restrict__ csr_exp, const int* __restrict__ row_start,
    const float* __restrict__ denom, const float* __restrict__ bias,
    float* __restrict__ out)
{
    int node = blockIdx.x * 4 + (threadIdx.x >> 6);
    int lane = threadIdx.x & 63;
    int col  = lane << 1;
    int head = lane >> 4;
    int b = row_start[node];
    int e = row_start[node + 1];
    float ax = 0.f, ay = 0.f;
    for (int k = b; k < e; ++k) {
        int   s  = csr_src[k];
        float a  = csr_exp[(k << 2) + head];
        float2 hv = *(const float2*)&h[s * OF + col];
        ax = fmaf(a, hv.x, ax);
        ay = fmaf(a, hv.y, ay);
    }
    float dn  = denom[(node << 2) + head] + 1e-16f;
    float inv = 1.0f / dn;
    float2 bs = *(const float2*)&bias[col];
    *(float2*)&out[node * OF + col] = make_float2(fmaf(ax, inv, bs.x), fmaf(ay, inv, bs.y));
}

// ---------------- BN: per-feature sum / sumsq reduction ----------------
__global__ __launch_bounds__(256) void k_bnred(
    const float* __restrict__ out, float* __restrict__ fsum, float* __restrict__ fsumsq)
{
    int f = threadIdx.x & 127;
    int r = blockIdx.x * 2 + (threadIdx.x >> 7);
    float s = 0.f, ss = 0.f;
    for (; r < NN; r += gridDim.x * 2) {
        float v = out[r * OF + f];
        s += v;
        ss = fmaf(v, v, ss);
    }
    atomicAdd(&fsum[f], s);
    atomicAdd(&fsumsq[f], ss);
}

__global__ void k_bnfin(
    const float* __restrict__ fsum, const float* __restrict__ fsumsq,
    const float* __restrict__ gamma, const float* __restrict__ beta,
    float* __restrict__ scale, float* __restrict__ shift)
{
    int f = threadIdx.x;  // 128 threads
    float mean = fsum[f] * (1.0f / NN);
    float var  = fsumsq[f] * (1.0f / NN) - mean * mean;
    float sc   = gamma[f] * rsqrtf(var + BN_EPS);
    scale[f] = sc;
    shift[f] = beta[f] - mean * sc;
}

// ---------------- fused BN apply + ELU ----------------
__global__ __launch_bounds__(256) void k_apply(
    float* __restrict__ out, const float* __restrict__ scale, const float* __restrict__ shift)
{
    int i    = blockIdx.x * 256 + threadIdx.x;
    int base = i << 2;
    int f    = base & 127;
    float4 v  = *(float4*)&out[base];
    float4 sc = *(const float4*)&scale[f];
    float4 sh = *(const float4*)&shift[f];
    float r0 = fmaf(v.x, sc.x, sh.x); r0 = r0 > 0.f ? r0 : expm1f(r0);
    float r1 = fmaf(v.y, sc.y, sh.y); r1 = r1 > 0.f ? r1 : expm1f(r1);
    float r2 = fmaf(v.z, sc.z, sh.z); r2 = r2 > 0.f ? r2 : expm1f(r2);
    float r3 = fmaf(v.w, sc.w, sh.w); r3 = r3 > 0.f ? r3 : expm1f(r3);
    *(float4*)&out[base] = make_float4(r0, r1, r2, r3);
}

extern "C" void kernel_launch(void* const* d_in, const int* in_sizes, int n_in,
                              void* d_out, int out_size, void* d_ws, size_t ws_size,
                              hipStream_t stream)
{
    const float* x     = (const float*)d_in[0];
    const int*   ei    = (const int*)d_in[1];   // [2, EE] int32
    const float* W     = (const float*)d_in[2];
    const float* att_s = (const float*)d_in[3];
    const float* att_d = (const float*)d_in[4];
    const float* bias  = (const float*)d_in[5];
    const float* gamma = (const float*)d_in[6];
    const float* beta  = (const float*)d_in[7];
    float* out = (float*)d_out;

    // workspace layout (~46.4 MB total)
    float* ws      = (float*)d_ws;
    float* h       = ws;                       // 6,400,000
    float* a_src   = h + 6400000;              //   200,000
    float* a_dst   = a_src + 200000;           //   200,000
    float* emax    = a_dst + 200000;           //   200,000
    float* denom   = emax + 200000;            //   200,000
    float* csr_exp = denom + 200000;           // 3,400,000
    float* fsum    = csr_exp + 3400000;        //       128
    float* fsumsq  = fsum + 128;               //       128
    float* scale   = fsumsq + 128;             //       128
    float* shift   = scale + 128;              //       128
    int* counts    = (int*)(shift + 128);      //    50,000
    int* row_start = counts + NN;              //    50,001
    int* fill_pos  = row_start + NN + 1;       //    50,000
    int* csr_src   = fill_pos + NN;            //   850,000

    hipMemsetAsync(emax, 0xFF, NN * 4 * sizeof(float), stream);  // -NaN sentinel, valid for sign-split max
    hipMemsetAsync(denom, 0, NN * 4 * sizeof(float), stream);
    hipMemsetAsync(counts, 0, NN * sizeof(int), stream);
    hipMemsetAsync(fsum, 0, 256 * sizeof(float), stream);        // fsum + fsumsq (contiguous)

    k_gemm<<<(NN + 31) / 32, 256, 0, stream>>>(x, W, att_s, att_d, h, a_src, a_dst);
    k_edge_max<<<(EP + 255) / 256, 256, 0, stream>>>(ei, a_src, a_dst, emax, counts);
    k_scan<<<1, 1024, 0, stream>>>(counts, row_start, fill_pos);
    k_edge_exp<<<(EP + 255) / 256, 256, 0, stream>>>(ei, a_src, a_dst, emax, denom, fill_pos, csr_src, csr_exp);
    k_gather<<<NN / 4, 256, 0, stream>>>(h, csr_src, csr_exp, row_start, denom, bias, out);
    k_bnred<<<512, 256, 0, stream>>>(out, fsum, fsumsq);
    k_bnfin<<<1, 128, 0, stream>>>(fsum, fsumsq, gamma, beta, scale, shift);
    k_apply<<<(NN * OF / 4 + 255) / 256, 256, 0, stream>>>(out, scale, shift);
}

// Round 2
// 419.026 us; speedup vs baseline: 1.6971x; 1.6971x over previous
//
#include <hip/hip_runtime.h>
#include <math.h>

#define NN 50000
#define EE 800000
#define EP (EE + NN)          // 850000 edges incl self-loops
#define INF_ 256
#define OF 128
#define NEG_SLOPE 0.2f
#define BN_EPS 1e-5f

// ---------------- GEMM: h = x @ W, plus a_src/a_dst attention dots ----------------
__global__ __launch_bounds__(256) void k_gemm(
    const float* __restrict__ x, const float* __restrict__ W,
    const float* __restrict__ att_s, const float* __restrict__ att_d,
    float* __restrict__ h, float* __restrict__ a_src, float* __restrict__ a_dst)
{
    __shared__ float xs[32 * 260];
    __shared__ float ws[64 * 128];
    const int tid  = threadIdx.x;
    const int row0 = blockIdx.x * 32;

    for (int i = tid; i < 32 * 64; i += 256) {
        int r  = i >> 6;
        int c4 = (i & 63) << 2;
        int rr = row0 + r; if (rr >= NN) rr = NN - 1;
        *(float4*)&xs[r * 260 + c4] = *(const float4*)&x[rr * INF_ + c4];
    }

    const int ra = tid >> 4;            // 0..15
    const int c0 = (tid & 15) << 2;     // 0,4,...,60
    float acc[2][8] = {};

    for (int kc = 0; kc < 4; ++kc) {
        __syncthreads();
        for (int i = tid; i < 64 * 32; i += 256) {
            int kk = i >> 5;
            int c4 = (i & 31) << 2;
            *(float4*)&ws[kk * 128 + c4] = *(const float4*)&W[(kc * 64 + kk) * OF + c4];
        }
        __syncthreads();
        #pragma unroll 8
        for (int kk = 0; kk < 64; ++kk) {
            float4 w0 = *(float4*)&ws[kk * 128 + c0];
            float4 w1 = *(float4*)&ws[kk * 128 + c0 + 64];
            float wv[8] = {w0.x, w0.y, w0.z, w0.w, w1.x, w1.y, w1.z, w1.w};
            float xa = xs[ra * 260 + (kc << 6) + kk];
            float xb = xs[(ra + 16) * 260 + (kc << 6) + kk];
            #pragma unroll
            for (int j = 0; j < 8; ++j) {
                acc[0][j] = fmaf(xa, wv[j], acc[0][j]);
                acc[1][j] = fmaf(xb, wv[j], acc[1][j]);
            }
        }
    }

    float4 As0 = *(const float4*)&att_s[c0];
    float4 As1 = *(const float4*)&att_s[c0 + 64];
    float4 Ad0 = *(const float4*)&att_d[c0];
    float4 Ad1 = *(const float4*)&att_d[c0 + 64];

    #pragma unroll
    for (int rr = 0; rr < 2; ++rr) {
        int row = row0 + ra + rr * 16;
        bool ok = (row < NN);
        if (ok) {
            *(float4*)&h[row * OF + c0]      = make_float4(acc[rr][0], acc[rr][1], acc[rr][2], acc[rr][3]);
            *(float4*)&h[row * OF + c0 + 64] = make_float4(acc[rr][4], acc[rr][5], acc[rr][6], acc[rr][7]);
        }
        float s0 = acc[rr][0]*As0.x + acc[rr][1]*As0.y + acc[rr][2]*As0.z + acc[rr][3]*As0.w;
        float s1 = acc[rr][4]*As1.x + acc[rr][5]*As1.y + acc[rr][6]*As1.z + acc[rr][7]*As1.w;
        float d0 = acc[rr][0]*Ad0.x + acc[rr][1]*Ad0.y + acc[rr][2]*Ad0.z + acc[rr][3]*Ad0.w;
        float d1 = acc[rr][4]*Ad1.x + acc[rr][5]*Ad1.y + acc[rr][6]*Ad1.z + acc[rr][7]*Ad1.w;
        s0 += __shfl_xor(s0, 1); s0 += __shfl_xor(s0, 2); s0 += __shfl_xor(s0, 4);
        s1 += __shfl_xor(s1, 1); s1 += __shfl_xor(s1, 2); s1 += __shfl_xor(s1, 4);
        d0 += __shfl_xor(d0, 1); d0 += __shfl_xor(d0, 2); d0 += __shfl_xor(d0, 4);
        d1 += __shfl_xor(d1, 1); d1 += __shfl_xor(d1, 2); d1 += __shfl_xor(d1, 4);
        if (ok && (tid & 7) == 0) {
            int hh = (tid >> 3) & 1;
            a_src[row * 4 + hh]     = s0;
            a_src[row * 4 + hh + 2] = s1;
            a_dst[row * 4 + hh]     = d0;
            a_dst[row * 4 + hh + 2] = d1;
        }
    }
}

// ---------------- degree counts over real edges only (self-loops added in scan) ----------------
__global__ __launch_bounds__(256) void k_count(const int* __restrict__ ei, int* __restrict__ counts)
{
    int idx = blockIdx.x * 256 + threadIdx.x;
    if (idx >= EE) return;
    atomicAdd(&counts[ei[EE + idx]], 1);
}

// ---------------- exclusive scan of (counts+1) -> row_start / fill_pos ----------------
__global__ __launch_bounds__(1024) void k_scan(
    const int* __restrict__ counts, int* __restrict__ row_start, int* __restrict__ fill_pos)
{
    __shared__ int part[1024];
    const int tid   = threadIdx.x;
    const int chunk = (NN + 1023) / 1024;  // 49
    int b = tid * chunk;
    int e = b + chunk; if (e > NN) e = NN; if (b > NN) b = NN;
    int s = 0;
    for (int i = b; i < e; ++i) s += counts[i] + 1;
    part[tid] = s;
    __syncthreads();
    for (int off = 1; off < 1024; off <<= 1) {
        int v = (tid >= off) ? part[tid - off] : 0;
        __syncthreads();
        part[tid] += v;
        __syncthreads();
    }
    int excl = tid ? part[tid - 1] : 0;
    for (int i = b; i < e; ++i) {
        row_start[i] = excl;
        fill_pos[i]  = excl;
        excl += counts[i] + 1;
    }
    if (tid == 1023) row_start[NN] = part[1023];
}

// ---------------- CSR fill (the only scatter left) ----------------
__global__ __launch_bounds__(256) void k_fill(
    const int* __restrict__ ei, int* __restrict__ fill_pos, int* __restrict__ csr_src)
{
    int idx = blockIdx.x * 256 + threadIdx.x;
    if (idx >= EP) return;
    int s, d;
    if (idx < EE) { s = ei[idx]; d = ei[EE + idx]; }
    else          { s = d = idx - EE; }
    int pos = atomicAdd(&fill_pos[d], 1);
    csr_src[pos] = s;
}

// ---------------- per-(node,head) softmax: no atomics ----------------
// pass 1: gather logits, write raw into csr_alpha (sequential per segment), track max
// pass 2: re-read (L2-hot), exp, accumulate sum, write back; store 1/(sum+eps)
__global__ __launch_bounds__(256) void k_alpha(
    const int* __restrict__ csr_src, const int* __restrict__ row_start,
    const float* __restrict__ a_src, const float* __restrict__ a_dst,
    float* __restrict__ csr_alpha, float* __restrict__ inv_denom)
{
    int gid = blockIdx.x * 256 + threadIdx.x;
    if (gid >= NN * 4) return;
    int node = gid >> 2;
    int hh   = gid & 3;
    int b = row_start[node];
    int e = row_start[node + 1];
    float ad = a_dst[node * 4 + hh];
    float m = -INFINITY;
    for (int k = b; k < e; ++k) {
        int s = csr_src[k];
        float v = a_src[s * 4 + hh] + ad;
        v = v > 0.f ? v : NEG_SLOPE * v;
        csr_alpha[(k << 2) + hh] = v;
        m = fmaxf(m, v);
    }
    float sum = 0.f;
    for (int k = b; k < e; ++k) {
        float v = csr_alpha[(k << 2) + hh];
        float xv = expf(v - m);
        sum += xv;
        csr_alpha[(k << 2) + hh] = xv;
    }
    inv_denom[gid] = 1.0f / (sum + 1e-16f);
}

// ---------------- gather: one wave per dst node, lane owns 2 output features ----------------
__global__ __launch_bounds__(256) void k_gather(
    const float* __restrict__ h, const int* __restrict__ csr_src,
    const float* __restrict__ csr_alpha, const int* __restrict__ row_start,
    const float* __restrict__ inv_denom, const float* __restrict__ bias,
    float* __restrict__ out)
{
    int node = blockIdx.x * 4 + (threadIdx.x >> 6);
    int lane = threadIdx.x & 63;
    int col  = lane << 1;
    int head = lane >> 4;
    int b = row_start[node];
    int e = row_start[node + 1];
    float ax = 0.f, ay = 0.f;
    int k = b;
    for (; k + 1 < e; k += 2) {
        int s0 = csr_src[k];
        int s1 = csr_src[k + 1];
        float a0 = csr_alpha[(k << 2) + head];
        float a1 = csr_alpha[((k + 1) << 2) + head];
        float2 h0 = *(const float2*)&h[s0 * OF + col];
        float2 h1 = *(const float2*)&h[s1 * OF + col];
        ax = fmaf(a0, h0.x, ax); ay = fmaf(a0, h0.y, ay);
        ax = fmaf(a1, h1.x, ax); ay = fmaf(a1, h1.y, ay);
    }
    if (k < e) {
        int s0 = csr_src[k];
        float a0 = csr_alpha[(k << 2) + head];
        float2 h0 = *(const float2*)&h[s0 * OF + col];
        ax = fmaf(a0, h0.x, ax); ay = fmaf(a0, h0.y, ay);
    }
    float inv = inv_denom[(node << 2) + head];
    float2 bs = *(const float2*)&bias[col];
    *(float2*)&out[node * OF + col] = make_float2(fmaf(ax, inv, bs.x), fmaf(ay, inv, bs.y));
}

// ---------------- BN: per-feature sum / sumsq reduction ----------------
__global__ __launch_bounds__(256) void k_bnred(
    const float* __restrict__ out, float* __restrict__ fsum, float* __restrict__ fsumsq)
{
    int f = threadIdx.x & 127;
    int r = blockIdx.x * 2 + (threadIdx.x >> 7);
    float s = 0.f, ss = 0.f;
    for (; r < NN; r += gridDim.x * 2) {
        float v = out[r * OF + f];
        s += v;
        ss = fmaf(v, v, ss);
    }
    atomicAdd(&fsum[f], s);
    atomicAdd(&fsumsq[f], ss);
}

__global__ void k_bnfin(
    const float* __restrict__ fsum, const float* __restrict__ fsumsq,
    const float* __restrict__ gamma, const float* __restrict__ beta,
    float* __restrict__ scale, float* __restrict__ shift)
{
    int f = threadIdx.x;  // 128 threads
    float mean = fsum[f] * (1.0f / NN);
    float var  = fsumsq[f] * (1.0f / NN) - mean * mean;
    float sc   = gamma[f] * rsqrtf(var + BN_EPS);
    scale[f] = sc;
    shift[f] = beta[f] - mean * sc;
}

// ---------------- fused BN apply + ELU ----------------
__global__ __launch_bounds__(256) void k_apply(
    float* __restrict__ out, const float* __restrict__ scale, const float* __restrict__ shift)
{
    int i    = blockIdx.x * 256 + threadIdx.x;
    int base = i << 2;
    int f    = base & 127;
    float4 v  = *(float4*)&out[base];
    float4 sc = *(const float4*)&scale[f];
    float4 sh = *(const float4*)&shift[f];
    float r0 = fmaf(v.x, sc.x, sh.x); r0 = r0 > 0.f ? r0 : expm1f(r0);
    float r1 = fmaf(v.y, sc.y, sh.y); r1 = r1 > 0.f ? r1 : expm1f(r1);
    float r2 = fmaf(v.z, sc.z, sh.z); r2 = r2 > 0.f ? r2 : expm1f(r2);
    float r3 = fmaf(v.w, sc.w, sh.w); r3 = r3 > 0.f ? r3 : expm1f(r3);
    *(float4*)&out[base] = make_float4(r0, r1, r2, r3);
}

extern "C" void kernel_launch(void* const* d_in, const int* in_sizes, int n_in,
                              void* d_out, int out_size, void* d_ws, size_t ws_size,
                              hipStream_t stream)
{
    const float* x     = (const float*)d_in[0];
    const int*   ei    = (const int*)d_in[1];
    const float* W     = (const float*)d_in[2];
    const float* att_s = (const float*)d_in[3];
    const float* att_d = (const float*)d_in[4];
    const float* bias  = (const float*)d_in[5];
    const float* gamma = (const float*)d_in[6];
    const float* beta  = (const float*)d_in[7];
    float* out = (float*)d_out;

    float* ws        = (float*)d_ws;
    float* h         = ws;                       // 6,400,000
    float* a_src     = h + 6400000;              //   200,000
    float* a_dst     = a_src + 200000;           //   200,000
    float* csr_alpha = a_dst + 200000;           // 3,400,000
    float* inv_denom = csr_alpha + 3400000;      //   200,000
    float* fsum      = inv_denom + 200000;       //       128
    float* fsumsq    = fsum + 128;               //       128
    float* scale     = fsumsq + 128;             //       128
    float* shift     = scale + 128;              //       128
    int* counts      = (int*)(shift + 128);      //    50,000
    int* row_start   = counts + NN;              //    50,001
    int* fill_pos    = row_start + NN + 1;       //    50,000
    int* csr_src     = fill_pos + NN;            //   850,000

    hipMemsetAsync(counts, 0, NN * sizeof(int), stream);
    hipMemsetAsync(fsum, 0, 256 * sizeof(float), stream);        // fsum + fsumsq contiguous

    k_gemm<<<(NN + 31) / 32, 256, 0, stream>>>(x, W, att_s, att_d, h, a_src, a_dst);
    k_count<<<(EE + 255) / 256, 256, 0, stream>>>(ei, counts);
    k_scan<<<1, 1024, 0, stream>>>(counts, row_start, fill_pos);
    k_fill<<<(EP + 255) / 256, 256, 0, stream>>>(ei, fill_pos, csr_src);
    k_alpha<<<(NN * 4 + 255) / 256, 256, 0, stream>>>(csr_src, row_start, a_src, a_dst, csr_alpha, inv_denom);
    k_gather<<<NN / 4, 256, 0, stream>>>(h, csr_src, csr_alpha, row_start, inv_denom, bias, out);
    k_bnred<<<512, 256, 0, stream>>>(out, fsum, fsumsq);
    k_bnfin<<<1, 128, 0, stream>>>(fsum, fsumsq, gamma, beta, scale, shift);
    k_apply<<<(NN * OF / 4 + 255) / 256, 256, 0, stream>>>(out, scale, shift);
}

// Round 3
// 320.939 us; speedup vs baseline: 2.2158x; 1.3056x over previous
//
#include <hip/hip_runtime.h>
#include <math.h>

#define NN 50000
#define EE 800000
#define EP (EE + NN)          // 850000 edges incl self-loops
#define INF_ 256
#define OF 128
#define NEG_SLOPE 0.2f
#define BN_EPS 1e-5f
#define NB 196                // ceil(NN/256)

// ---------------- GEMM: h = x @ W, plus a_src/a_dst attention dots ----------------
__global__ __launch_bounds__(256) void k_gemm(
    const float* __restrict__ x, const float* __restrict__ W,
    const float* __restrict__ att_s, const float* __restrict__ att_d,
    float* __restrict__ h, float* __restrict__ a_src, float* __restrict__ a_dst)
{
    __shared__ float xs[32 * 260];
    __shared__ float ws[64 * 128];
    const int tid  = threadIdx.x;
    const int row0 = blockIdx.x * 32;

    for (int i = tid; i < 32 * 64; i += 256) {
        int r  = i >> 6;
        int c4 = (i & 63) << 2;
        int rr = row0 + r; if (rr >= NN) rr = NN - 1;
        *(float4*)&xs[r * 260 + c4] = *(const float4*)&x[rr * INF_ + c4];
    }

    const int ra = tid >> 4;            // 0..15
    const int c0 = (tid & 15) << 2;     // 0,4,...,60
    float acc[2][8] = {};

    for (int kc = 0; kc < 4; ++kc) {
        __syncthreads();
        for (int i = tid; i < 64 * 32; i += 256) {
            int kk = i >> 5;
            int c4 = (i & 31) << 2;
            *(float4*)&ws[kk * 128 + c4] = *(const float4*)&W[(kc * 64 + kk) * OF + c4];
        }
        __syncthreads();
        #pragma unroll 8
        for (int kk = 0; kk < 64; ++kk) {
            float4 w0 = *(float4*)&ws[kk * 128 + c0];
            float4 w1 = *(float4*)&ws[kk * 128 + c0 + 64];
            float wv[8] = {w0.x, w0.y, w0.z, w0.w, w1.x, w1.y, w1.z, w1.w};
            float xa = xs[ra * 260 + (kc << 6) + kk];
            float xb = xs[(ra + 16) * 260 + (kc << 6) + kk];
            #pragma unroll
            for (int j = 0; j < 8; ++j) {
                acc[0][j] = fmaf(xa, wv[j], acc[0][j]);
                acc[1][j] = fmaf(xb, wv[j], acc[1][j]);
            }
        }
    }

    float4 As0 = *(const float4*)&att_s[c0];
    float4 As1 = *(const float4*)&att_s[c0 + 64];
    float4 Ad0 = *(const float4*)&att_d[c0];
    float4 Ad1 = *(const float4*)&att_d[c0 + 64];

    #pragma unroll
    for (int rr = 0; rr < 2; ++rr) {
        int row = row0 + ra + rr * 16;
        bool ok = (row < NN);
        if (ok) {
            *(float4*)&h[row * OF + c0]      = make_float4(acc[rr][0], acc[rr][1], acc[rr][2], acc[rr][3]);
            *(float4*)&h[row * OF + c0 + 64] = make_float4(acc[rr][4], acc[rr][5], acc[rr][6], acc[rr][7]);
        }
        float s0 = acc[rr][0]*As0.x + acc[rr][1]*As0.y + acc[rr][2]*As0.z + acc[rr][3]*As0.w;
        float s1 = acc[rr][4]*As1.x + acc[rr][5]*As1.y + acc[rr][6]*As1.z + acc[rr][7]*As1.w;
        float d0 = acc[rr][0]*Ad0.x + acc[rr][1]*Ad0.y + acc[rr][2]*Ad0.z + acc[rr][3]*Ad0.w;
        float d1 = acc[rr][4]*Ad1.x + acc[rr][5]*Ad1.y + acc[rr][6]*Ad1.z + acc[rr][7]*Ad1.w;
        s0 += __shfl_xor(s0, 1); s0 += __shfl_xor(s0, 2); s0 += __shfl_xor(s0, 4);
        s1 += __shfl_xor(s1, 1); s1 += __shfl_xor(s1, 2); s1 += __shfl_xor(s1, 4);
        d0 += __shfl_xor(d0, 1); d0 += __shfl_xor(d0, 2); d0 += __shfl_xor(d0, 4);
        d1 += __shfl_xor(d1, 1); d1 += __shfl_xor(d1, 2); d1 += __shfl_xor(d1, 4);
        if (ok && (tid & 7) == 0) {
            int hh = (tid >> 3) & 1;
            a_src[row * 4 + hh]     = s0;
            a_src[row * 4 + hh + 2] = s1;
            a_dst[row * 4 + hh]     = d0;
            a_dst[row * 4 + hh + 2] = d1;
        }
    }
}

// ---------------- degree counts over real edges only ----------------
__global__ __launch_bounds__(256) void k_count(const int* __restrict__ ei, int* __restrict__ counts)
{
    int idx = blockIdx.x * 256 + threadIdx.x;
    if (idx >= EE) return;
    atomicAdd(&counts[ei[EE + idx]], 1);
}

// ---------------- hierarchical scan, stage 1: per-block sums ----------------
__global__ __launch_bounds__(256) void k_blocksum(const int* __restrict__ counts, int* __restrict__ partials)
{
    int i = blockIdx.x * 256 + threadIdx.x;
    int v = (i < NN) ? counts[i] + 1 : 0;
    v += __shfl_xor(v, 1);  v += __shfl_xor(v, 2);  v += __shfl_xor(v, 4);
    v += __shfl_xor(v, 8);  v += __shfl_xor(v, 16); v += __shfl_xor(v, 32);
    __shared__ int wsum[4];
    if ((threadIdx.x & 63) == 0) wsum[threadIdx.x >> 6] = v;
    __syncthreads();
    if (threadIdx.x == 0) partials[blockIdx.x] = wsum[0] + wsum[1] + wsum[2] + wsum[3];
}

// ---------------- stage 2: scan the 196 partials (in place -> exclusive offsets) ----------------
__global__ __launch_bounds__(256) void k_scanpart(int* __restrict__ partials)
{
    __shared__ int sm[256];
    int t = threadIdx.x;
    int v = (t < NB) ? partials[t] : 0;
    sm[t] = v;
    __syncthreads();
    for (int off = 1; off < 256; off <<= 1) {
        int u = (t >= off) ? sm[t - off] : 0;
        __syncthreads();
        sm[t] += u;
        __syncthreads();
    }
    if (t < NB) partials[t] = sm[t] - v;   // exclusive
}

// ---------------- stage 3: per-block exclusive scan + offset -> row_start / fill_pos ----------------
__global__ __launch_bounds__(256) void k_writerows(
    const int* __restrict__ counts, const int* __restrict__ partials,
    int* __restrict__ row_start, int* __restrict__ fill_pos)
{
    __shared__ int sm[256];
    int t = threadIdx.x;
    int i = blockIdx.x * 256 + t;
    int v = (i < NN) ? counts[i] + 1 : 0;
    sm[t] = v;
    __syncthreads();
    for (int off = 1; off < 256; off <<= 1) {
        int u = (t >= off) ? sm[t - off] : 0;
        __syncthreads();
        sm[t] += u;
        __syncthreads();
    }
    int excl = partials[blockIdx.x] + sm[t] - v;
    if (i < NN) { row_start[i] = excl; fill_pos[i] = excl; }
    if (i == NN) row_start[NN] = excl;
}

// ---------------- CSR fill ----------------
__global__ __launch_bounds__(256) void k_fill(
    const int* __restrict__ ei, int* __restrict__ fill_pos, int* __restrict__ csr_src)
{
    int idx = blockIdx.x * 256 + threadIdx.x;
    if (idx >= EP) return;
    int s, d;
    if (idx < EE) { s = ei[idx]; d = ei[EE + idx]; }
    else          { s = d = idx - EE; }
    int pos = atomicAdd(&fill_pos[d], 1);
    csr_src[pos] = s;
}

// ---------------- per-(node,head) softmax: no atomics ----------------
__global__ __launch_bounds__(256) void k_alpha(
    const int* __restrict__ csr_src, const int* __restrict__ row_start,
    const float* __restrict__ a_src, const float* __restrict__ a_dst,
    float* __restrict__ csr_alpha, float* __restrict__ inv_denom)
{
    int gid = blockIdx.x * 256 + threadIdx.x;
    if (gid >= NN * 4) return;
    int node = gid >> 2;
    int hh   = gid & 3;
    int b = row_start[node];
    int e = row_start[node + 1];
    float ad = a_dst[node * 4 + hh];
    float m = -INFINITY;
    for (int k = b; k < e; ++k) {
        int s = csr_src[k];
        float v = a_src[s * 4 + hh] + ad;
        v = v > 0.f ? v : NEG_SLOPE * v;
        csr_alpha[(k << 2) + hh] = v;
        m = fmaxf(m, v);
    }
    float sum = 0.f;
    for (int k = b; k < e; ++k) {
        float v = csr_alpha[(k << 2) + hh];
        float xv = expf(v - m);
        sum += xv;
        csr_alpha[(k << 2) + hh] = xv;
    }
    inv_denom[gid] = 1.0f / (sum + 1e-16f);
}

// ---------------- gather: one wave per dst node, lane owns 2 output features ----------------
__global__ __launch_bounds__(256) void k_gather(
    const float* __restrict__ h, const int* __restrict__ csr_src,
    const float* __restrict__ csr_alpha, const int* __restrict__ row_start,
    const float* __restrict__ inv_denom, const float* __restrict__ bias,
    float* __restrict__ out)
{
    int node = blockIdx.x * 4 + (threadIdx.x >> 6);
    int lane = threadIdx.x & 63;
    int col  = lane << 1;
    int head = lane >> 4;
    int b = row_start[node];
    int e = row_start[node + 1];
    float ax = 0.f, ay = 0.f;
    int k = b;
    for (; k + 1 < e; k += 2) {
        int s0 = csr_src[k];
        int s1 = csr_src[k + 1];
        float a0 = csr_alpha[(k << 2) + head];
        float a1 = csr_alpha[((k + 1) << 2) + head];
        float2 h0 = *(const float2*)&h[s0 * OF + col];
        float2 h1 = *(const float2*)&h[s1 * OF + col];
        ax = fmaf(a0, h0.x, ax); ay = fmaf(a0, h0.y, ay);
        ax = fmaf(a1, h1.x, ax); ay = fmaf(a1, h1.y, ay);
    }
    if (k < e) {
        int s0 = csr_src[k];
        float a0 = csr_alpha[(k << 2) + head];
        float2 h0 = *(const float2*)&h[s0 * OF + col];
        ax = fmaf(a0, h0.x, ax); ay = fmaf(a0, h0.y, ay);
    }
    float inv = inv_denom[(node << 2) + head];
    float2 bs = *(const float2*)&bias[col];
    *(float2*)&out[node * OF + col] = make_float2(fmaf(ax, inv, bs.x), fmaf(ay, inv, bs.y));
}

// ---------------- BN: per-feature sum / sumsq reduction ----------------
__global__ __launch_bounds__(256) void k_bnred(
    const float* __restrict__ out, float* __restrict__ fsum, float* __restrict__ fsumsq)
{
    int f = threadIdx.x & 127;
    int r = blockIdx.x * 2 + (threadIdx.x >> 7);
    float s = 0.f, ss = 0.f;
    for (; r < NN; r += gridDim.x * 2) {
        float v = out[r * OF + f];
        s += v;
        ss = fmaf(v, v, ss);
    }
    atomicAdd(&fsum[f], s);
    atomicAdd(&fsumsq[f], ss);
}

__global__ void k_bnfin(
    const float* __restrict__ fsum, const float* __restrict__ fsumsq,
    const float* __restrict__ gamma, const float* __restrict__ beta,
    float* __restrict__ scale, float* __restrict__ shift)
{
    int f = threadIdx.x;  // 128 threads
    float mean = fsum[f] * (1.0f / NN);
    float var  = fsumsq[f] * (1.0f / NN) - mean * mean;
    float sc   = gamma[f] * rsqrtf(var + BN_EPS);
    scale[f] = sc;
    shift[f] = beta[f] - mean * sc;
}

// ---------------- fused BN apply + ELU ----------------
__global__ __launch_bounds__(256) void k_apply(
    float* __restrict__ out, const float* __restrict__ scale, const float* __restrict__ shift)
{
    int i    = blockIdx.x * 256 + threadIdx.x;
    int base = i << 2;
    int f    = base & 127;
    float4 v  = *(float4*)&out[base];
    float4 sc = *(const float4*)&scale[f];
    float4 sh = *(const float4*)&shift[f];
    float r0 = fmaf(v.x, sc.x, sh.x); r0 = r0 > 0.f ? r0 : expm1f(r0);
    float r1 = fmaf(v.y, sc.y, sh.y); r1 = r1 > 0.f ? r1 : expm1f(r1);
    float r2 = fmaf(v.z, sc.z, sh.z); r2 = r2 > 0.f ? r2 : expm1f(r2);
    float r3 = fmaf(v.w, sc.w, sh.w); r3 = r3 > 0.f ? r3 : expm1f(r3);
    *(float4*)&out[base] = make_float4(r0, r1, r2, r3);
}

extern "C" void kernel_launch(void* const* d_in, const int* in_sizes, int n_in,
                              void* d_out, int out_size, void* d_ws, size_t ws_size,
                              hipStream_t stream)
{
    const float* x     = (const float*)d_in[0];
    const int*   ei    = (const int*)d_in[1];
    const float* W     = (const float*)d_in[2];
    const float* att_s = (const float*)d_in[3];
    const float* att_d = (const float*)d_in[4];
    const float* bias  = (const float*)d_in[5];
    const float* gamma = (const float*)d_in[6];
    const float* beta  = (const float*)d_in[7];
    float* out = (float*)d_out;

    float* ws        = (float*)d_ws;
    float* h         = ws;                       // 6,400,000
    float* a_src     = h + 6400000;              //   200,000
    float* a_dst     = a_src + 200000;           //   200,000
    float* csr_alpha = a_dst + 200000;           // 3,400,000
    float* inv_denom = csr_alpha + 3400000;      //   200,000
    float* fsum      = inv_denom + 200000;       //       128
    float* fsumsq    = fsum + 128;               //       128
    float* scale     = fsumsq + 128;             //       128
    float* shift     = scale + 128;              //       128
    int* counts      = (int*)(shift + 128);      //    50,000
    int* row_start   = counts + NN;              //    50,001
    int* fill_pos    = row_start + NN + 1;       //    50,000
    int* csr_src     = fill_pos + NN;            //   850,000
    int* partials    = csr_src + EP;             //       256

    hipMemsetAsync(counts, 0, NN * sizeof(int), stream);
    hipMemsetAsync(fsum, 0, 256 * sizeof(float), stream);        // fsum + fsumsq contiguous

    k_gemm<<<(NN + 31) / 32, 256, 0, stream>>>(x, W, att_s, att_d, h, a_src, a_dst);
    k_count<<<(EE + 255) / 256, 256, 0, stream>>>(ei, counts);
    k_blocksum<<<NB, 256, 0, stream>>>(counts, partials);
    k_scanpart<<<1, 256, 0, stream>>>(partials);
    k_writerows<<<NB, 256, 0, stream>>>(counts, partials, row_start, fill_pos);
    k_fill<<<(EP + 255) / 256, 256, 0, stream>>>(ei, fill_pos, csr_src);
    k_alpha<<<(NN * 4 + 255) / 256, 256, 0, stream>>>(csr_src, row_start, a_src, a_dst, csr_alpha, inv_denom);
    k_gather<<<NN / 4, 256, 0, stream>>>(h, csr_src, csr_alpha, row_start, inv_denom, bias, out);
    k_bnred<<<512, 256, 0, stream>>>(out, fsum, fsumsq);
    k_bnfin<<<1, 128, 0, stream>>>(fsum, fsumsq, gamma, beta, scale, shift);
    k_apply<<<(NN * OF / 4 + 255) / 256, 256, 0, stream>>>(out, scale, shift);
}

// Round 4
// 306.164 us; speedup vs baseline: 2.3227x; 1.0483x over previous
//
#include <hip/hip_runtime.h>
#include <math.h>

#define NN 50000
#define EE 800000
#define EP (EE + NN)          // 850000 edges incl self-loops
#define INF_ 256
#define OF 128
#define NEG_SLOPE 0.2f
#define BN_EPS 1e-5f
#define NB 196                // ceil(NN/256)

// ---------------- GEMM: h = x @ W, plus a_src/a_dst attention dots ----------------
// block: 256 threads, 64 rows x 128 cols. tx=tid&15 -> cols {4tx..4tx+3, 4tx+64..4tx+67},
// ty=tid>>4 -> rows {4ty..4ty+3}. 32 FMA per k-step vs ~47cy LDS -> VALU-bound.
// LDS 49.4KB -> 3 blocks/CU (12 waves/CU).
__global__ __launch_bounds__(256) void k_gemm(
    const float* __restrict__ x, const float* __restrict__ W,
    const float* __restrict__ att_s, const float* __restrict__ att_d,
    float* __restrict__ h, float* __restrict__ a_src, float* __restrict__ a_dst)
{
    __shared__ float xs[64 * 65];    // [row][k], pad 65: x-reads spread over 4 banks, conflict-free
    __shared__ float ws[64 * 128];   // [k][col], measured zero-conflict layout
    const int tid  = threadIdx.x;
    const int row0 = blockIdx.x * 64;
    const int tx = tid & 15;
    const int ty = tid >> 4;
    const int c0 = tx << 2;          // 0..60
    const int r0 = ty << 2;          // 0..60
    float acc[4][8] = {};

    for (int kc = 0; kc < 4; ++kc) {
        __syncthreads();
        // stage x chunk: 64 rows x 64 k (b32 writes; pad-65 rows are not 16B aligned)
        #pragma unroll
        for (int it = 0; it < 4; ++it) {
            int i  = tid + (it << 8);     // 0..1023
            int r  = i >> 4;              // 0..63
            int c4 = (i & 15) << 2;       // 0..60
            int rr = row0 + r; if (rr >= NN) rr = NN - 1;
            float4 v = *(const float4*)&x[rr * INF_ + (kc << 6) + c4];
            float* p = &xs[r * 65 + c4];
            p[0] = v.x; p[1] = v.y; p[2] = v.z; p[3] = v.w;
        }
        // stage W chunk: 64 k x 128 cols
        #pragma unroll
        for (int it = 0; it < 8; ++it) {
            int i  = tid + (it << 8);     // 0..2047
            int kk = i >> 5;
            int c4 = (i & 31) << 2;
            *(float4*)&ws[kk * 128 + c4] = *(const float4*)&W[(kc * 64 + kk) * OF + c4];
        }
        __syncthreads();
        #pragma unroll 4
        for (int kk = 0; kk < 64; ++kk) {
            float4 w0 = *(float4*)&ws[kk * 128 + c0];
            float4 w1 = *(float4*)&ws[kk * 128 + c0 + 64];
            float xv[4];
            #pragma unroll
            for (int i = 0; i < 4; ++i) xv[i] = xs[(r0 + i) * 65 + kk];
            #pragma unroll
            for (int i = 0; i < 4; ++i) {
                acc[i][0] = fmaf(xv[i], w0.x, acc[i][0]);
                acc[i][1] = fmaf(xv[i], w0.y, acc[i][1]);
                acc[i][2] = fmaf(xv[i], w0.z, acc[i][2]);
                acc[i][3] = fmaf(xv[i], w0.w, acc[i][3]);
                acc[i][4] = fmaf(xv[i], w1.x, acc[i][4]);
                acc[i][5] = fmaf(xv[i], w1.y, acc[i][5]);
                acc[i][6] = fmaf(xv[i], w1.z, acc[i][6]);
                acc[i][7] = fmaf(xv[i], w1.w, acc[i][7]);
            }
        }
    }

    // epilogue: h writes + attention dots (8-lane xor reduce, same proven mapping)
    float4 As0 = *(const float4*)&att_s[c0];
    float4 As1 = *(const float4*)&att_s[c0 + 64];
    float4 Ad0 = *(const float4*)&att_d[c0];
    float4 Ad1 = *(const float4*)&att_d[c0 + 64];

    #pragma unroll
    for (int i = 0; i < 4; ++i) {
        int row = row0 + r0 + i;
        bool ok = (row < NN);
        if (ok) {
            *(float4*)&h[row * OF + c0]      = make_float4(acc[i][0], acc[i][1], acc[i][2], acc[i][3]);
            *(float4*)&h[row * OF + c0 + 64] = make_float4(acc[i][4], acc[i][5], acc[i][6], acc[i][7]);
        }
        float s0 = acc[i][0]*As0.x + acc[i][1]*As0.y + acc[i][2]*As0.z + acc[i][3]*As0.w;
        float s1 = acc[i][4]*As1.x + acc[i][5]*As1.y + acc[i][6]*As1.z + acc[i][7]*As1.w;
        float d0 = acc[i][0]*Ad0.x + acc[i][1]*Ad0.y + acc[i][2]*Ad0.z + acc[i][3]*Ad0.w;
        float d1 = acc[i][4]*Ad1.x + acc[i][5]*Ad1.y + acc[i][6]*Ad1.z + acc[i][7]*Ad1.w;
        s0 += __shfl_xor(s0, 1); s0 += __shfl_xor(s0, 2); s0 += __shfl_xor(s0, 4);
        s1 += __shfl_xor(s1, 1); s1 += __shfl_xor(s1, 2); s1 += __shfl_xor(s1, 4);
        d0 += __shfl_xor(d0, 1); d0 += __shfl_xor(d0, 2); d0 += __shfl_xor(d0, 4);
        d1 += __shfl_xor(d1, 1); d1 += __shfl_xor(d1, 2); d1 += __shfl_xor(d1, 4);
        if (ok && (tid & 7) == 0) {
            int hh = (tid >> 3) & 1;
            a_src[row * 4 + hh]     = s0;
            a_src[row * 4 + hh + 2] = s1;
            a_dst[row * 4 + hh]     = d0;
            a_dst[row * 4 + hh + 2] = d1;
        }
    }
}

// ---------------- degree counts over real edges only ----------------
__global__ __launch_bounds__(256) void k_count(const int* __restrict__ ei, int* __restrict__ counts)
{
    int idx = blockIdx.x * 256 + threadIdx.x;
    if (idx >= EE) return;
    atomicAdd(&counts[ei[EE + idx]], 1);
}

// ---------------- hierarchical scan, stage 1: per-block sums ----------------
__global__ __launch_bounds__(256) void k_blocksum(const int* __restrict__ counts, int* __restrict__ partials)
{
    int i = blockIdx.x * 256 + threadIdx.x;
    int v = (i < NN) ? counts[i] + 1 : 0;
    v += __shfl_xor(v, 1);  v += __shfl_xor(v, 2);  v += __shfl_xor(v, 4);
    v += __shfl_xor(v, 8);  v += __shfl_xor(v, 16); v += __shfl_xor(v, 32);
    __shared__ int wsum[4];
    if ((threadIdx.x & 63) == 0) wsum[threadIdx.x >> 6] = v;
    __syncthreads();
    if (threadIdx.x == 0) partials[blockIdx.x] = wsum[0] + wsum[1] + wsum[2] + wsum[3];
}

// ---------------- stage 2: scan the 196 partials (in place -> exclusive offsets) ----------------
__global__ __launch_bounds__(256) void k_scanpart(int* __restrict__ partials)
{
    __shared__ int sm[256];
    int t = threadIdx.x;
    int v = (t < NB) ? partials[t] : 0;
    sm[t] = v;
    __syncthreads();
    for (int off = 1; off < 256; off <<= 1) {
        int u = (t >= off) ? sm[t - off] : 0;
        __syncthreads();
        sm[t] += u;
        __syncthreads();
    }
    if (t < NB) partials[t] = sm[t] - v;   // exclusive
}

// ---------------- stage 3: per-block exclusive scan + offset -> row_start / fill_pos ----------------
__global__ __launch_bounds__(256) void k_writerows(
    const int* __restrict__ counts, const int* __restrict__ partials,
    int* __restrict__ row_start, int* __restrict__ fill_pos)
{
    __shared__ int sm[256];
    int t = threadIdx.x;
    int i = blockIdx.x * 256 + t;
    int v = (i < NN) ? counts[i] + 1 : 0;
    sm[t] = v;
    __syncthreads();
    for (int off = 1; off < 256; off <<= 1) {
        int u = (t >= off) ? sm[t - off] : 0;
        __syncthreads();
        sm[t] += u;
        __syncthreads();
    }
    int excl = partials[blockIdx.x] + sm[t] - v;
    if (i < NN) { row_start[i] = excl; fill_pos[i] = excl; }
    if (i == NN) row_start[NN] = excl;
}

// ---------------- CSR fill ----------------
__global__ __launch_bounds__(256) void k_fill(
    const int* __restrict__ ei, int* __restrict__ fill_pos, int* __restrict__ csr_src)
{
    int idx = blockIdx.x * 256 + threadIdx.x;
    if (idx >= EP) return;
    int s, d;
    if (idx < EE) { s = ei[idx]; d = ei[EE + idx]; }
    else          { s = d = idx - EE; }
    int pos = atomicAdd(&fill_pos[d], 1);
    csr_src[pos] = s;
}

// ---------------- per-(node,head) softmax: no atomics ----------------
__global__ __launch_bounds__(256) void k_alpha(
    const int* __restrict__ csr_src, const int* __restrict__ row_start,
    const float* __restrict__ a_src, const float* __restrict__ a_dst,
    float* __restrict__ csr_alpha, float* __restrict__ inv_denom)
{
    int gid = blockIdx.x * 256 + threadIdx.x;
    if (gid >= NN * 4) return;
    int node = gid >> 2;
    int hh   = gid & 3;
    int b = row_start[node];
    int e = row_start[node + 1];
    float ad = a_dst[node * 4 + hh];
    float m = -INFINITY;
    for (int k = b; k < e; ++k) {
        int s = csr_src[k];
        float v = a_src[s * 4 + hh] + ad;
        v = v > 0.f ? v : NEG_SLOPE * v;
        csr_alpha[(k << 2) + hh] = v;
        m = fmaxf(m, v);
    }
    float sum = 0.f;
    for (int k = b; k < e; ++k) {
        float v = csr_alpha[(k << 2) + hh];
        float xv = expf(v - m);
        sum += xv;
        csr_alpha[(k << 2) + hh] = xv;
    }
    inv_denom[gid] = 1.0f / (sum + 1e-16f);
}

// ---------------- gather: one wave per dst node, lane owns 2 output features ----------------
__global__ __launch_bounds__(256) void k_gather(
    const float* __restrict__ h, const int* __restrict__ csr_src,
    const float* __restrict__ csr_alpha, const int* __restrict__ row_start,
    const float* __restrict__ inv_denom, const float* __restrict__ bias,
    float* __restrict__ out)
{
    int node = blockIdx.x * 4 + (threadIdx.x >> 6);
    int lane = threadIdx.x & 63;
    int col  = lane << 1;
    int head = lane >> 4;
    int b = row_start[node];
    int e = row_start[node + 1];
    float ax = 0.f, ay = 0.f;
    int k = b;
    for (; k + 1 < e; k += 2) {
        int s0 = csr_src[k];
        int s1 = csr_src[k + 1];
        float a0 = csr_alpha[(k << 2) + head];
        float a1 = csr_alpha[((k + 1) << 2) + head];
        float2 h0 = *(const float2*)&h[s0 * OF + col];
        float2 h1 = *(const float2*)&h[s1 * OF + col];
        ax = fmaf(a0, h0.x, ax); ay = fmaf(a0, h0.y, ay);
        ax = fmaf(a1, h1.x, ax); ay = fmaf(a1, h1.y, ay);
    }
    if (k < e) {
        int s0 = csr_src[k];
        float a0 = csr_alpha[(k << 2) + head];
        float2 h0 = *(const float2*)&h[s0 * OF + col];
        ax = fmaf(a0, h0.x, ax); ay = fmaf(a0, h0.y, ay);
    }
    float inv = inv_denom[(node << 2) + head];
    float2 bs = *(const float2*)&bias[col];
    *(float2*)&out[node * OF + col] = make_float2(fmaf(ax, inv, bs.x), fmaf(ay, inv, bs.y));
}

// ---------------- BN: per-feature sum / sumsq reduction ----------------
__global__ __launch_bounds__(256) void k_bnred(
    const float* __restrict__ out, float* __restrict__ fsum, float* __restrict__ fsumsq)
{
    int f = threadIdx.x & 127;
    int r = blockIdx.x * 2 + (threadIdx.x >> 7);
    float s = 0.f, ss = 0.f;
    for (; r < NN; r += gridDim.x * 2) {
        float v = out[r * OF + f];
        s += v;
        ss = fmaf(v, v, ss);
    }
    atomicAdd(&fsum[f], s);
    atomicAdd(&fsumsq[f], ss);
}

__global__ void k_bnfin(
    const float* __restrict__ fsum, const float* __restrict__ fsumsq,
    const float* __restrict__ gamma, const float* __restrict__ beta,
    float* __restrict__ scale, float* __restrict__ shift)
{
    int f = threadIdx.x;  // 128 threads
    float mean = fsum[f] * (1.0f / NN);
    float var  = fsumsq[f] * (1.0f / NN) - mean * mean;
    float sc   = gamma[f] * rsqrtf(var + BN_EPS);
    scale[f] = sc;
    shift[f] = beta[f] - mean * sc;
}

// ---------------- fused BN apply + ELU ----------------
__global__ __launch_bounds__(256) void k_apply(
    float* __restrict__ out, const float* __restrict__ scale, const float* __restrict__ shift)
{
    int i    = blockIdx.x * 256 + threadIdx.x;
    int base = i << 2;
    int f    = base & 127;
    float4 v  = *(float4*)&out[base];
    float4 sc = *(const float4*)&scale[f];
    float4 sh = *(const float4*)&shift[f];
    float r0 = fmaf(v.x, sc.x, sh.x); r0 = r0 > 0.f ? r0 : expm1f(r0);
    float r1 = fmaf(v.y, sc.y, sh.y); r1 = r1 > 0.f ? r1 : expm1f(r1);
    float r2 = fmaf(v.z, sc.z, sh.z); r2 = r2 > 0.f ? r2 : expm1f(r2);
    float r3 = fmaf(v.w, sc.w, sh.w); r3 = r3 > 0.f ? r3 : expm1f(r3);
    *(float4*)&out[base] = make_float4(r0, r1, r2, r3);
}

extern "C" void kernel_launch(void* const* d_in, const int* in_sizes, int n_in,
                              void* d_out, int out_size, void* d_ws, size_t ws_size,
                              hipStream_t stream)
{
    const float* x     = (const float*)d_in[0];
    const int*   ei    = (const int*)d_in[1];
    const float* W     = (const float*)d_in[2];
    const float* att_s = (const float*)d_in[3];
    const float* att_d = (const float*)d_in[4];
    const float* bias  = (const float*)d_in[5];
    const float* gamma = (const float*)d_in[6];
    const float* beta  = (const float*)d_in[7];
    float* out = (float*)d_out;

    float* ws        = (float*)d_ws;
    float* h         = ws;                       // 6,400,000
    float* a_src     = h + 6400000;              //   200,000
    float* a_dst     = a_src + 200000;           //   200,000
    float* csr_alpha = a_dst + 200000;           // 3,400,000
    float* inv_denom = csr_alpha + 3400000;      //   200,000
    float* fsum      = inv_denom + 200000;       //       128
    float* fsumsq    = fsum + 128;               //       128
    float* scale     = fsumsq + 128;             //       128
    float* shift     = scale + 128;              //       128
    int* counts      = (int*)(shift + 128);      //    50,000
    int* row_start   = counts + NN;              //    50,001
    int* fill_pos    = row_start + NN + 1;       //    50,000
    int* csr_src     = fill_pos + NN;            //   850,000
    int* partials    = csr_src + EP;             //       256

    hipMemsetAsync(counts, 0, NN * sizeof(int), stream);
    hipMemsetAsync(fsum, 0, 256 * sizeof(float), stream);        // fsum + fsumsq contiguous

    k_gemm<<<(NN + 63) / 64, 256, 0, stream>>>(x, W, att_s, att_d, h, a_src, a_dst);
    k_count<<<(EE + 255) / 256, 256, 0, stream>>>(ei, counts);
    k_blocksum<<<NB, 256, 0, stream>>>(counts, partials);
    k_scanpart<<<1, 256, 0, stream>>>(partials);
    k_writerows<<<NB, 256, 0, stream>>>(counts, partials, row_start, fill_pos);
    k_fill<<<(EP + 255) / 256, 256, 0, stream>>>(ei, fill_pos, csr_src);
    k_alpha<<<(NN * 4 + 255) / 256, 256, 0, stream>>>(csr_src, row_start, a_src, a_dst, csr_alpha, inv_denom);
    k_gather<<<NN / 4, 256, 0, stream>>>(h, csr_src, csr_alpha, row_start, inv_denom, bias, out);
    k_bnred<<<512, 256, 0, stream>>>(out, fsum, fsumsq);
    k_bnfin<<<1, 128, 0, stream>>>(fsum, fsumsq, gamma, beta, scale, shift);
    k_apply<<<(NN * OF / 4 + 255) / 256, 256, 0, stream>>>(out, scale, shift);
}

// Round 5
// 280.935 us; speedup vs baseline: 2.5313x; 1.0898x over previous
//
#include <hip/hip_runtime.h>
#include <hip/hip_fp16.h>
#include <math.h>

#define NN 50000
#define EE 800000
#define EP (EE + NN)          // 850000 edges incl self-loops
#define INF_ 256
#define OF 128
#define NEG_SLOPE 0.2f
#define BN_EPS 1e-5f
#define NB 196                // ceil(NN/256)

// ---------------- GEMM: h = x @ W (h stored fp16), plus a_src/a_dst attention dots ----------------
__global__ __launch_bounds__(256) void k_gemm(
    const float* __restrict__ x, const float* __restrict__ W,
    const float* __restrict__ att_s, const float* __restrict__ att_d,
    __half* __restrict__ h, float* __restrict__ a_src, float* __restrict__ a_dst)
{
    __shared__ float xs[64 * 65];    // [row][k], pad 65
    __shared__ float ws[64 * 128];   // [k][col]
    const int tid  = threadIdx.x;
    const int row0 = blockIdx.x * 64;
    const int tx = tid & 15;
    const int ty = tid >> 4;
    const int c0 = tx << 2;          // 0..60
    const int r0 = ty << 2;          // 0..60
    float acc[4][8] = {};

    for (int kc = 0; kc < 4; ++kc) {
        __syncthreads();
        #pragma unroll
        for (int it = 0; it < 4; ++it) {
            int i  = tid + (it << 8);
            int r  = i >> 4;
            int c4 = (i & 15) << 2;
            int rr = row0 + r; if (rr >= NN) rr = NN - 1;
            float4 v = *(const float4*)&x[rr * INF_ + (kc << 6) + c4];
            float* p = &xs[r * 65 + c4];
            p[0] = v.x; p[1] = v.y; p[2] = v.z; p[3] = v.w;
        }
        #pragma unroll
        for (int it = 0; it < 8; ++it) {
            int i  = tid + (it << 8);
            int kk = i >> 5;
            int c4 = (i & 31) << 2;
            *(float4*)&ws[kk * 128 + c4] = *(const float4*)&W[(kc * 64 + kk) * OF + c4];
        }
        __syncthreads();
        #pragma unroll 4
        for (int kk = 0; kk < 64; ++kk) {
            float4 w0 = *(float4*)&ws[kk * 128 + c0];
            float4 w1 = *(float4*)&ws[kk * 128 + c0 + 64];
            float xv[4];
            #pragma unroll
            for (int i = 0; i < 4; ++i) xv[i] = xs[(r0 + i) * 65 + kk];
            #pragma unroll
            for (int i = 0; i < 4; ++i) {
                acc[i][0] = fmaf(xv[i], w0.x, acc[i][0]);
                acc[i][1] = fmaf(xv[i], w0.y, acc[i][1]);
                acc[i][2] = fmaf(xv[i], w0.z, acc[i][2]);
                acc[i][3] = fmaf(xv[i], w0.w, acc[i][3]);
                acc[i][4] = fmaf(xv[i], w1.x, acc[i][4]);
                acc[i][5] = fmaf(xv[i], w1.y, acc[i][5]);
                acc[i][6] = fmaf(xv[i], w1.z, acc[i][6]);
                acc[i][7] = fmaf(xv[i], w1.w, acc[i][7]);
            }
        }
    }

    float4 As0 = *(const float4*)&att_s[c0];
    float4 As1 = *(const float4*)&att_s[c0 + 64];
    float4 Ad0 = *(const float4*)&att_d[c0];
    float4 Ad1 = *(const float4*)&att_d[c0 + 64];

    #pragma unroll
    for (int i = 0; i < 4; ++i) {
        int row = row0 + r0 + i;
        bool ok = (row < NN);
        if (ok) {
            union { __half2 h2[2]; uint2 u; } p0, p1;
            p0.h2[0] = __floats2half2_rn(acc[i][0], acc[i][1]);
            p0.h2[1] = __floats2half2_rn(acc[i][2], acc[i][3]);
            p1.h2[0] = __floats2half2_rn(acc[i][4], acc[i][5]);
            p1.h2[1] = __floats2half2_rn(acc[i][6], acc[i][7]);
            *(uint2*)&h[row * OF + c0]      = p0.u;
            *(uint2*)&h[row * OF + c0 + 64] = p1.u;
        }
        float s0 = acc[i][0]*As0.x + acc[i][1]*As0.y + acc[i][2]*As0.z + acc[i][3]*As0.w;
        float s1 = acc[i][4]*As1.x + acc[i][5]*As1.y + acc[i][6]*As1.z + acc[i][7]*As1.w;
        float d0 = acc[i][0]*Ad0.x + acc[i][1]*Ad0.y + acc[i][2]*Ad0.z + acc[i][3]*Ad0.w;
        float d1 = acc[i][4]*Ad1.x + acc[i][5]*Ad1.y + acc[i][6]*Ad1.z + acc[i][7]*Ad1.w;
        s0 += __shfl_xor(s0, 1); s0 += __shfl_xor(s0, 2); s0 += __shfl_xor(s0, 4);
        s1 += __shfl_xor(s1, 1); s1 += __shfl_xor(s1, 2); s1 += __shfl_xor(s1, 4);
        d0 += __shfl_xor(d0, 1); d0 += __shfl_xor(d0, 2); d0 += __shfl_xor(d0, 4);
        d1 += __shfl_xor(d1, 1); d1 += __shfl_xor(d1, 2); d1 += __shfl_xor(d1, 4);
        if (ok && (tid & 7) == 0) {
            int hh = (tid >> 3) & 1;
            a_src[row * 4 + hh]     = s0;
            a_src[row * 4 + hh + 2] = s1;
            a_dst[row * 4 + hh]     = d0;
            a_dst[row * 4 + hh + 2] = d1;
        }
    }
}

// ---------------- degree counts over real edges only ----------------
__global__ __launch_bounds__(256) void k_count(const int* __restrict__ ei, int* __restrict__ counts)
{
    int idx = blockIdx.x * 256 + threadIdx.x;
    if (idx >= EE) return;
    atomicAdd(&counts[ei[EE + idx]], 1);
}

// ---------------- hierarchical scan, stage 1: per-block sums ----------------
__global__ __launch_bounds__(256) void k_blocksum(const int* __restrict__ counts, int* __restrict__ partials)
{
    int i = blockIdx.x * 256 + threadIdx.x;
    int v = (i < NN) ? counts[i] + 1 : 0;
    v += __shfl_xor(v, 1);  v += __shfl_xor(v, 2);  v += __shfl_xor(v, 4);
    v += __shfl_xor(v, 8);  v += __shfl_xor(v, 16); v += __shfl_xor(v, 32);
    __shared__ int wsum[4];
    if ((threadIdx.x & 63) == 0) wsum[threadIdx.x >> 6] = v;
    __syncthreads();
    if (threadIdx.x == 0) partials[blockIdx.x] = wsum[0] + wsum[1] + wsum[2] + wsum[3];
}

// ---------------- stage 2: scan the 196 partials ----------------
__global__ __launch_bounds__(256) void k_scanpart(int* __restrict__ partials)
{
    __shared__ int sm[256];
    int t = threadIdx.x;
    int v = (t < NB) ? partials[t] : 0;
    sm[t] = v;
    __syncthreads();
    for (int off = 1; off < 256; off <<= 1) {
        int u = (t >= off) ? sm[t - off] : 0;
        __syncthreads();
        sm[t] += u;
        __syncthreads();
    }
    if (t < NB) partials[t] = sm[t] - v;   // exclusive
}

// ---------------- stage 3: per-block scan + offset -> row_start / fill_pos ----------------
__global__ __launch_bounds__(256) void k_writerows(
    const int* __restrict__ counts, const int* __restrict__ partials,
    int* __restrict__ row_start, int* __restrict__ fill_pos)
{
    __shared__ int sm[256];
    int t = threadIdx.x;
    int i = blockIdx.x * 256 + t;
    int v = (i < NN) ? counts[i] + 1 : 0;
    sm[t] = v;
    __syncthreads();
    for (int off = 1; off < 256; off <<= 1) {
        int u = (t >= off) ? sm[t - off] : 0;
        __syncthreads();
        sm[t] += u;
        __syncthreads();
    }
    int excl = partials[blockIdx.x] + sm[t] - v;
    if (i < NN) { row_start[i] = excl; fill_pos[i] = excl; }
    if (i == NN) row_start[NN] = excl;
}

// ---------------- CSR fill ----------------
__global__ __launch_bounds__(256) void k_fill(
    const int* __restrict__ ei, int* __restrict__ fill_pos, int* __restrict__ csr_src)
{
    int idx = blockIdx.x * 256 + threadIdx.x;
    if (idx >= EP) return;
    int s, d;
    if (idx < EE) { s = ei[idx]; d = ei[EE + idx]; }
    else          { s = d = idx - EE; }
    int pos = atomicAdd(&fill_pos[d], 1);
    csr_src[pos] = s;
}

// ---------------- per-(node,head) softmax: no atomics ----------------
__global__ __launch_bounds__(256) void k_alpha(
    const int* __restrict__ csr_src, const int* __restrict__ row_start,
    const float* __restrict__ a_src, const float* __restrict__ a_dst,
    float* __restrict__ csr_alpha, float* __restrict__ inv_denom)
{
    int gid = blockIdx.x * 256 + threadIdx.x;
    if (gid >= NN * 4) return;
    int node = gid >> 2;
    int hh   = gid & 3;
    int b = row_start[node];
    int e = row_start[node + 1];
    float ad = a_dst[node * 4 + hh];
    float m = -INFINITY;
    for (int k = b; k < e; ++k) {
        int s = csr_src[k];
        float v = a_src[s * 4 + hh] + ad;
        v = v > 0.f ? v : NEG_SLOPE * v;
        csr_alpha[(k << 2) + hh] = v;
        m = fmaxf(m, v);
    }
    float sum = 0.f;
    for (int k = b; k < e; ++k) {
        float v = csr_alpha[(k << 2) + hh];
        float xv = expf(v - m);
        sum += xv;
        csr_alpha[(k << 2) + hh] = xv;
    }
    inv_denom[gid] = 1.0f / (sum + 1e-16f);
}

// ---------------- gather: one wave per dst node, lane owns 2 cols (fp16 h), 4-edge unroll ----------------
__global__ __launch_bounds__(256) void k_gather(
    const __half* __restrict__ h, const int* __restrict__ csr_src,
    const float* __restrict__ csr_alpha, const int* __restrict__ row_start,
    const float* __restrict__ inv_denom, const float* __restrict__ bias,
    float* __restrict__ out)
{
    int node = blockIdx.x * 4 + (threadIdx.x >> 6);
    int lane = threadIdx.x & 63;
    int col  = lane << 1;
    int head = lane >> 4;
    int b = row_start[node];
    int e = row_start[node + 1];
    float ax = 0.f, ay = 0.f;
    int k = b;
    for (; k + 3 < e; k += 4) {
        int s0 = csr_src[k];
        int s1 = csr_src[k + 1];
        int s2 = csr_src[k + 2];
        int s3 = csr_src[k + 3];
        float a0 = csr_alpha[(k << 2) + head];
        float a1 = csr_alpha[((k + 1) << 2) + head];
        float a2 = csr_alpha[((k + 2) << 2) + head];
        float a3 = csr_alpha[((k + 3) << 2) + head];
        float2 h0 = __half22float2(*(const __half2*)&h[s0 * OF + col]);
        float2 h1 = __half22float2(*(const __half2*)&h[s1 * OF + col]);
        float2 h2 = __half22float2(*(const __half2*)&h[s2 * OF + col]);
        float2 h3 = __half22float2(*(const __half2*)&h[s3 * OF + col]);
        ax = fmaf(a0, h0.x, ax); ay = fmaf(a0, h0.y, ay);
        ax = fmaf(a1, h1.x, ax); ay = fmaf(a1, h1.y, ay);
        ax = fmaf(a2, h2.x, ax); ay = fmaf(a2, h2.y, ay);
        ax = fmaf(a3, h3.x, ax); ay = fmaf(a3, h3.y, ay);
    }
    for (; k < e; ++k) {
        int s0 = csr_src[k];
        float a0 = csr_alpha[(k << 2) + head];
        float2 h0 = __half22float2(*(const __half2*)&h[s0 * OF + col]);
        ax = fmaf(a0, h0.x, ax); ay = fmaf(a0, h0.y, ay);
    }
    float inv = inv_denom[(node << 2) + head];
    float2 bs = *(const float2*)&bias[col];
    *(float2*)&out[node * OF + col] = make_float2(fmaf(ax, inv, bs.x), fmaf(ay, inv, bs.y));
}

// ---------------- BN: per-feature sum / sumsq reduction ----------------
__global__ __launch_bounds__(256) void k_bnred(
    const float* __restrict__ out, float* __restrict__ fsum, float* __restrict__ fsumsq)
{
    int f = threadIdx.x & 127;
    int r = blockIdx.x * 2 + (threadIdx.x >> 7);
    float s = 0.f, ss = 0.f;
    for (; r < NN; r += gridDim.x * 2) {
        float v = out[r * OF + f];
        s += v;
        ss = fmaf(v, v, ss);
    }
    atomicAdd(&fsum[f], s);
    atomicAdd(&fsumsq[f], ss);
}

__global__ void k_bnfin(
    const float* __restrict__ fsum, const float* __restrict__ fsumsq,
    const float* __restrict__ gamma, const float* __restrict__ beta,
    float* __restrict__ scale, float* __restrict__ shift)
{
    int f = threadIdx.x;  // 128 threads
    float mean = fsum[f] * (1.0f / NN);
    float var  = fsumsq[f] * (1.0f / NN) - mean * mean;
    float sc   = gamma[f] * rsqrtf(var + BN_EPS);
    scale[f] = sc;
    shift[f] = beta[f] - mean * sc;
}

// ---------------- fused BN apply + ELU ----------------
__global__ __launch_bounds__(256) void k_apply(
    float* __restrict__ out, const float* __restrict__ scale, const float* __restrict__ shift)
{
    int i    = blockIdx.x * 256 + threadIdx.x;
    int base = i << 2;
    int f    = base & 127;
    float4 v  = *(float4*)&out[base];
    float4 sc = *(const float4*)&scale[f];
    float4 sh = *(const float4*)&shift[f];
    float r0 = fmaf(v.x, sc.x, sh.x); r0 = r0 > 0.f ? r0 : expm1f(r0);
    float r1 = fmaf(v.y, sc.y, sh.y); r1 = r1 > 0.f ? r1 : expm1f(r1);
    float r2 = fmaf(v.z, sc.z, sh.z); r2 = r2 > 0.f ? r2 : expm1f(r2);
    float r3 = fmaf(v.w, sc.w, sh.w); r3 = r3 > 0.f ? r3 : expm1f(r3);
    *(float4*)&out[base] = make_float4(r0, r1, r2, r3);
}

extern "C" void kernel_launch(void* const* d_in, const int* in_sizes, int n_in,
                              void* d_out, int out_size, void* d_ws, size_t ws_size,
                              hipStream_t stream)
{
    const float* x     = (const float*)d_in[0];
    const int*   ei    = (const int*)d_in[1];
    const float* W     = (const float*)d_in[2];
    const float* att_s = (const float*)d_in[3];
    const float* att_d = (const float*)d_in[4];
    const float* bias  = (const float*)d_in[5];
    const float* gamma = (const float*)d_in[6];
    const float* beta  = (const float*)d_in[7];
    float* out = (float*)d_out;

    float* ws        = (float*)d_ws;
    __half* h        = (__half*)ws;              // 6.4M halves (region reserves 6.4M floats)
    float* a_src     = ws + 6400000;             //   200,000
    float* a_dst     = a_src + 200000;           //   200,000
    float* csr_alpha = a_dst + 200000;           // 3,400,000
    float* inv_denom = csr_alpha + 3400000;      //   200,000
    float* fsum      = inv_denom + 200000;       //       128
    float* fsumsq    = fsum + 128;               //       128
    float* scale     = fsumsq + 128;             //       128
    float* shift     = scale + 128;              //       128
    int* counts      = (int*)(shift + 128);      //    50,000
    int* row_start   = counts + NN;              //    50,001
    int* fill_pos    = row_start + NN + 1;       //    50,000
    int* csr_src     = fill_pos + NN;            //   850,000
    int* partials    = csr_src + EP;             //       256

    hipMemsetAsync(counts, 0, NN * sizeof(int), stream);
    hipMemsetAsync(fsum, 0, 256 * sizeof(float), stream);        // fsum + fsumsq contiguous

    k_gemm<<<(NN + 63) / 64, 256, 0, stream>>>(x, W, att_s, att_d, h, a_src, a_dst);
    k_count<<<(EE + 255) / 256, 256, 0, stream>>>(ei, counts);
    k_blocksum<<<NB, 256, 0, stream>>>(counts, partials);
    k_scanpart<<<1, 256, 0, stream>>>(partials);
    k_writerows<<<NB, 256, 0, stream>>>(counts, partials, row_start, fill_pos);
    k_fill<<<(EP + 255) / 256, 256, 0, stream>>>(ei, fill_pos, csr_src);
    k_alpha<<<(NN * 4 + 255) / 256, 256, 0, stream>>>(csr_src, row_start, a_src, a_dst, csr_alpha, inv_denom);
    k_gather<<<NN / 4, 256, 0, stream>>>(h, csr_src, csr_alpha, row_start, inv_denom, bias, out);
    k_bnred<<<512, 256, 0, stream>>>(out, fsum, fsumsq);
    k_bnfin<<<1, 128, 0, stream>>>(fsum, fsumsq, gamma, beta, scale, shift);
    k_apply<<<(NN * OF / 4 + 255) / 256, 256, 0, stream>>>(out, scale, shift);
}

// Round 6
// 272.267 us; speedup vs baseline: 2.6119x; 1.0318x over previous
//
#include <hip/hip_runtime.h>
#include <hip/hip_fp16.h>
#include <math.h>

#define NN 50000
#define EE 800000
#define EP (EE + NN)          // 850000 edges incl self-loops
#define INF_ 256
#define OF 128
#define NEG_SLOPE 0.2f
#define BN_EPS 1e-5f
#define NB 196                // ceil(NN/256)

typedef _Float16 half8 __attribute__((ext_vector_type(8)));
typedef float floatx4 __attribute__((ext_vector_type(4)));

// ---------------- GEMM (MFMA fp16): h = x @ W, plus a_src/a_dst dots ----------------
// 64 rows x 128 cols per block, 4 waves; wave w owns rows [w*16, w*16+16) x all 128 cols
// = 8 tiles of mfma_f32_16x16x32_f16. x,W converted f32->fp16 at staging.
// LDS stride 72 halves = 144B: 16B-aligned for b128 frag reads, 2-way bank alias (free).
__global__ __launch_bounds__(256) void k_gemm(
    const float* __restrict__ x, const float* __restrict__ W,
    const float* __restrict__ att_s, const float* __restrict__ att_d,
    _Float16* __restrict__ h, float* __restrict__ a_src, float* __restrict__ a_dst)
{
    __shared__ __align__(16) _Float16 smem[64 * 72 + 128 * 72];  // 27648 B -> 5 blocks/CU
    _Float16* xh = smem;             // [64 rows][72] (k-major)
    _Float16* wh = smem + 64 * 72;   // [128 cols][72] (k-major, transposed W)

    const int tid  = threadIdx.x;
    const int l    = tid & 63;
    const int w    = tid >> 6;           // wave 0..3
    const int row0 = blockIdx.x * 64;
    const int lrow = l & 15;             // frag row (A) / col (B) / col (D)
    const int lk8  = (l >> 4) << 3;      // frag k base

    floatx4 acc[8];
    #pragma unroll
    for (int t = 0; t < 8; ++t) acc[t] = (floatx4){0.f, 0.f, 0.f, 0.f};

    for (int kc = 0; kc < 4; ++kc) {
        __syncthreads();
        // stage x chunk: 64 rows x 64 k, f32 -> fp16
        #pragma unroll
        for (int it = 0; it < 4; ++it) {
            int i  = tid + (it << 8);
            int r  = i >> 4;
            int c4 = (i & 15) << 2;
            int rr = row0 + r; if (rr >= NN) rr = NN - 1;
            float4 v = *(const float4*)&x[rr * INF_ + (kc << 6) + c4];
            _Float16* p = &xh[r * 72 + c4];
            p[0] = (_Float16)v.x; p[1] = (_Float16)v.y;
            p[2] = (_Float16)v.z; p[3] = (_Float16)v.w;
        }
        // stage W chunk transposed: wh[col][k], 64 k x 128 cols
        #pragma unroll
        for (int it = 0; it < 8; ++it) {
            int i  = tid + (it << 8);    // 0..2047
            int k  = i >> 5;             // 0..63
            int c4 = (i & 31) << 2;      // 0..124
            float4 v = *(const float4*)&W[(kc * 64 + k) * OF + c4];
            wh[(c4 + 0) * 72 + k] = (_Float16)v.x;
            wh[(c4 + 1) * 72 + k] = (_Float16)v.y;
            wh[(c4 + 2) * 72 + k] = (_Float16)v.z;
            wh[(c4 + 3) * 72 + k] = (_Float16)v.w;
        }
        __syncthreads();
        // 2 MFMA k-steps of 32 per chunk
        #pragma unroll
        for (int ks = 0; ks < 2; ++ks) {
            half8 a = *(half8*)&xh[(w * 16 + lrow) * 72 + (ks << 5) + lk8];
            #pragma unroll
            for (int t = 0; t < 8; ++t) {
                half8 b = *(half8*)&wh[(t * 16 + lrow) * 72 + (ks << 5) + lk8];
                acc[t] = __builtin_amdgcn_mfma_f32_16x16x32_f16(a, b, acc[t], 0, 0, 0);
            }
        }
    }

    // ---- attention dots straight from accumulator fragments ----
    // D layout: col = lane&15 (within tile t: col = 16t + lrow), row = 4*(l>>4) + reg
    float as_c[8], ad_c[8];
    #pragma unroll
    for (int t = 0; t < 8; ++t) { as_c[t] = att_s[t * 16 + lrow]; ad_c[t] = att_d[t * 16 + lrow]; }
    float my_s = 0.f, my_d = 0.f;
    #pragma unroll
    for (int hh = 0; hh < 4; ++hh) {
        #pragma unroll
        for (int reg = 0; reg < 4; ++reg) {
            float ps = acc[2*hh][reg] * as_c[2*hh] + acc[2*hh+1][reg] * as_c[2*hh+1];
            float pd = acc[2*hh][reg] * ad_c[2*hh] + acc[2*hh+1][reg] * ad_c[2*hh+1];
            ps += __shfl_xor(ps, 1); ps += __shfl_xor(ps, 2); ps += __shfl_xor(ps, 4); ps += __shfl_xor(ps, 8);
            pd += __shfl_xor(pd, 1); pd += __shfl_xor(pd, 2); pd += __shfl_xor(pd, 4); pd += __shfl_xor(pd, 8);
            if (lrow == hh * 4 + reg) { my_s = ps; my_d = pd; }
        }
    }
    {
        int myreg = lrow & 3, myhh = lrow >> 2;
        int myrow = row0 + w * 16 + ((l >> 4) << 2) + myreg;
        if (myrow < NN) { a_src[myrow * 4 + myhh] = my_s; a_dst[myrow * 4 + myhh] = my_d; }
    }

    // ---- repack D through LDS, coalesced fp16 h stores ----
    __syncthreads();                       // all waves done reading xh/wh
    _Float16* ldso = smem + w * 2048;      // 16 rows x 128 cols per wave
    #pragma unroll
    for (int t = 0; t < 8; ++t)
        #pragma unroll
        for (int reg = 0; reg < 4; ++reg)
            ldso[(((l >> 4) << 2) + reg) * 128 + t * 16 + lrow] = (_Float16)acc[t][reg];
    __syncthreads();
    {
        _Float16* gdst = h + (size_t)(row0 + w * 16) * OF;   // rows>=NN land in reserved slack, never read
        #pragma unroll
        for (int q = 0; q < 4; ++q) {
            int off = (q << 9) + (l << 3);                   // halves
            *(half8*)&gdst[off] = *(half8*)&ldso[off];
        }
    }
}

// ---------------- degree counts over real edges only ----------------
__global__ __launch_bounds__(256) void k_count(const int* __restrict__ ei, int* __restrict__ counts)
{
    int idx = blockIdx.x * 256 + threadIdx.x;
    if (idx >= EE) return;
    atomicAdd(&counts[ei[EE + idx]], 1);
}

// ---------------- hierarchical scan, stage 1: per-block sums ----------------
__global__ __launch_bounds__(256) void k_blocksum(const int* __restrict__ counts, int* __restrict__ partials)
{
    int i = blockIdx.x * 256 + threadIdx.x;
    int v = (i < NN) ? counts[i] + 1 : 0;
    v += __shfl_xor(v, 1);  v += __shfl_xor(v, 2);  v += __shfl_xor(v, 4);
    v += __shfl_xor(v, 8);  v += __shfl_xor(v, 16); v += __shfl_xor(v, 32);
    __shared__ int wsum[4];
    if ((threadIdx.x & 63) == 0) wsum[threadIdx.x >> 6] = v;
    __syncthreads();
    if (threadIdx.x == 0) partials[blockIdx.x] = wsum[0] + wsum[1] + wsum[2] + wsum[3];
}

// ---------------- stage 2: scan the 196 partials ----------------
__global__ __launch_bounds__(256) void k_scanpart(int* __restrict__ partials)
{
    __shared__ int sm[256];
    int t = threadIdx.x;
    int v = (t < NB) ? partials[t] : 0;
    sm[t] = v;
    __syncthreads();
    for (int off = 1; off < 256; off <<= 1) {
        int u = (t >= off) ? sm[t - off] : 0;
        __syncthreads();
        sm[t] += u;
        __syncthreads();
    }
    if (t < NB) partials[t] = sm[t] - v;   // exclusive
}

// ---------------- stage 3: per-block scan + offset -> row_start / fill_pos ----------------
__global__ __launch_bounds__(256) void k_writerows(
    const int* __restrict__ counts, const int* __restrict__ partials,
    int* __restrict__ row_start, int* __restrict__ fill_pos)
{
    __shared__ int sm[256];
    int t = threadIdx.x;
    int i = blockIdx.x * 256 + t;
    int v = (i < NN) ? counts[i] + 1 : 0;
    sm[t] = v;
    __syncthreads();
    for (int off = 1; off < 256; off <<= 1) {
        int u = (t >= off) ? sm[t - off] : 0;
        __syncthreads();
        sm[t] += u;
        __syncthreads();
    }
    int excl = partials[blockIdx.x] + sm[t] - v;
    if (i < NN) { row_start[i] = excl; fill_pos[i] = excl; }
    if (i == NN) row_start[NN] = excl;
}

// ---------------- CSR fill ----------------
__global__ __launch_bounds__(256) void k_fill(
    const int* __restrict__ ei, int* __restrict__ fill_pos, int* __restrict__ csr_src)
{
    int idx = blockIdx.x * 256 + threadIdx.x;
    if (idx >= EP) return;
    int s, d;
    if (idx < EE) { s = ei[idx]; d = ei[EE + idx]; }
    else          { s = d = idx - EE; }
    int pos = atomicAdd(&fill_pos[d], 1);
    csr_src[pos] = s;
}

// ---------------- per-(node,head) softmax: no atomics ----------------
__global__ __launch_bounds__(256) void k_alpha(
    const int* __restrict__ csr_src, const int* __restrict__ row_start,
    const float* __restrict__ a_src, const float* __restrict__ a_dst,
    float* __restrict__ csr_alpha, float* __restrict__ inv_denom)
{
    int gid = blockIdx.x * 256 + threadIdx.x;
    if (gid >= NN * 4) return;
    int node = gid >> 2;
    int hh   = gid & 3;
    int b = row_start[node];
    int e = row_start[node + 1];
    float ad = a_dst[node * 4 + hh];
    float m = -INFINITY;
    for (int k = b; k < e; ++k) {
        int s = csr_src[k];
        float v = a_src[s * 4 + hh] + ad;
        v = v > 0.f ? v : NEG_SLOPE * v;
        csr_alpha[(k << 2) + hh] = v;
        m = fmaxf(m, v);
    }
    float sum = 0.f;
    for (int k = b; k < e; ++k) {
        float v = csr_alpha[(k << 2) + hh];
        float xv = expf(v - m);
        sum += xv;
        csr_alpha[(k << 2) + hh] = xv;
    }
    inv_denom[gid] = 1.0f / (sum + 1e-16f);
}

// ---------------- gather: one wave per dst node, lane owns 2 cols (fp16 h), 4-edge unroll ----------------
__global__ __launch_bounds__(256) void k_gather(
    const __half* __restrict__ h, const int* __restrict__ csr_src,
    const float* __restrict__ csr_alpha, const int* __restrict__ row_start,
    const float* __restrict__ inv_denom, const float* __restrict__ bias,
    float* __restrict__ out)
{
    int node = blockIdx.x * 4 + (threadIdx.x >> 6);
    int lane = threadIdx.x & 63;
    int col  = lane << 1;
    int head = lane >> 4;
    int b = row_start[node];
    int e = row_start[node + 1];
    float ax = 0.f, ay = 0.f;
    int k = b;
    for (; k + 3 < e; k += 4) {
        int s0 = csr_src[k];
        int s1 = csr_src[k + 1];
        int s2 = csr_src[k + 2];
        int s3 = csr_src[k + 3];
        float a0 = csr_alpha[(k << 2) + head];
        float a1 = csr_alpha[((k + 1) << 2) + head];
        float a2 = csr_alpha[((k + 2) << 2) + head];
        float a3 = csr_alpha[((k + 3) << 2) + head];
        float2 h0 = __half22float2(*(const __half2*)&h[s0 * OF + col]);
        float2 h1 = __half22float2(*(const __half2*)&h[s1 * OF + col]);
        float2 h2 = __half22float2(*(const __half2*)&h[s2 * OF + col]);
        float2 h3 = __half22float2(*(const __half2*)&h[s3 * OF + col]);
        ax = fmaf(a0, h0.x, ax); ay = fmaf(a0, h0.y, ay);
        ax = fmaf(a1, h1.x, ax); ay = fmaf(a1, h1.y, ay);
        ax = fmaf(a2, h2.x, ax); ay = fmaf(a2, h2.y, ay);
        ax = fmaf(a3, h3.x, ax); ay = fmaf(a3, h3.y, ay);
    }
    for (; k < e; ++k) {
        int s0 = csr_src[k];
        float a0 = csr_alpha[(k << 2) + head];
        float2 h0 = __half22float2(*(const __half2*)&h[s0 * OF + col]);
        ax = fmaf(a0, h0.x, ax); ay = fmaf(a0, h0.y, ay);
    }
    float inv = inv_denom[(node << 2) + head];
    float2 bs = *(const float2*)&bias[col];
    *(float2*)&out[node * OF + col] = make_float2(fmaf(ax, inv, bs.x), fmaf(ay, inv, bs.y));
}

// ---------------- BN: per-feature sum / sumsq reduction ----------------
__global__ __launch_bounds__(256) void k_bnred(
    const float* __restrict__ out, float* __restrict__ fsum, float* __restrict__ fsumsq)
{
    int f = threadIdx.x & 127;
    int r = blockIdx.x * 2 + (threadIdx.x >> 7);
    float s = 0.f, ss = 0.f;
    for (; r < NN; r += gridDim.x * 2) {
        float v = out[r * OF + f];
        s += v;
        ss = fmaf(v, v, ss);
    }
    atomicAdd(&fsum[f], s);
    atomicAdd(&fsumsq[f], ss);
}

__global__ void k_bnfin(
    const float* __restrict__ fsum, const float* __restrict__ fsumsq,
    const float* __restrict__ gamma, const float* __restrict__ beta,
    float* __restrict__ scale, float* __restrict__ shift)
{
    int f = threadIdx.x;  // 128 threads
    float mean = fsum[f] * (1.0f / NN);
    float var  = fsumsq[f] * (1.0f / NN) - mean * mean;
    float sc   = gamma[f] * rsqrtf(var + BN_EPS);
    scale[f] = sc;
    shift[f] = beta[f] - mean * sc;
}

// ---------------- fused BN apply + ELU ----------------
__global__ __launch_bounds__(256) void k_apply(
    float* __restrict__ out, const float* __restrict__ scale, const float* __restrict__ shift)
{
    int i    = blockIdx.x * 256 + threadIdx.x;
    int base = i << 2;
    int f    = base & 127;
    float4 v  = *(float4*)&out[base];
    float4 sc = *(const float4*)&scale[f];
    float4 sh = *(const float4*)&shift[f];
    float r0 = fmaf(v.x, sc.x, sh.x); r0 = r0 > 0.f ? r0 : expm1f(r0);
    float r1 = fmaf(v.y, sc.y, sh.y); r1 = r1 > 0.f ? r1 : expm1f(r1);
    float r2 = fmaf(v.z, sc.z, sh.z); r2 = r2 > 0.f ? r2 : expm1f(r2);
    float r3 = fmaf(v.w, sc.w, sh.w); r3 = r3 > 0.f ? r3 : expm1f(r3);
    *(float4*)&out[base] = make_float4(r0, r1, r2, r3);
}

extern "C" void kernel_launch(void* const* d_in, const int* in_sizes, int n_in,
                              void* d_out, int out_size, void* d_ws, size_t ws_size,
                              hipStream_t stream)
{
    const float* x     = (const float*)d_in[0];
    const int*   ei    = (const int*)d_in[1];
    const float* W     = (const float*)d_in[2];
    const float* att_s = (const float*)d_in[3];
    const float* att_d = (const float*)d_in[4];
    const float* bias  = (const float*)d_in[5];
    const float* gamma = (const float*)d_in[6];
    const float* beta  = (const float*)d_in[7];
    float* out = (float*)d_out;

    float* ws        = (float*)d_ws;
    _Float16* h      = (_Float16*)ws;            // 50048*128 halves in 6.4M-float slot
    float* a_src     = ws + 6400000;             //   200,000
    float* a_dst     = a_src + 200000;           //   200,000
    float* csr_alpha = a_dst + 200000;           // 3,400,000
    float* inv_denom = csr_alpha + 3400000;      //   200,000
    float* fsum      = inv_denom + 200000;       //       128
    float* fsumsq    = fsum + 128;               //       128
    float* scale     = fsumsq + 128;             //       128
    float* shift     = scale + 128;              //       128
    int* counts      = (int*)(shift + 128);      //    50,000
    int* row_start   = counts + NN;              //    50,001
    int* fill_pos    = row_start + NN + 1;       //    50,000
    int* csr_src     = fill_pos + NN;            //   850,000
    int* partials    = csr_src + EP;             //       256

    hipMemsetAsync(counts, 0, NN * sizeof(int), stream);
    hipMemsetAsync(fsum, 0, 256 * sizeof(float), stream);        // fsum + fsumsq contiguous

    k_gemm<<<(NN + 63) / 64, 256, 0, stream>>>(x, W, att_s, att_d, h, a_src, a_dst);
    k_count<<<(EE + 255) / 256, 256, 0, stream>>>(ei, counts);
    k_blocksum<<<NB, 256, 0, stream>>>(counts, partials);
    k_scanpart<<<1, 256, 0, stream>>>(partials);
    k_writerows<<<NB, 256, 0, stream>>>(counts, partials, row_start, fill_pos);
    k_fill<<<(EP + 255) / 256, 256, 0, stream>>>(ei, fill_pos, csr_src);
    k_alpha<<<(NN * 4 + 255) / 256, 256, 0, stream>>>(csr_src, row_start, a_src, a_dst, csr_alpha, inv_denom);
    k_gather<<<NN / 4, 256, 0, stream>>>((const __half*)h, csr_src, csr_alpha, row_start, inv_denom, bias, out);
    k_bnred<<<512, 256, 0, stream>>>(out, fsum, fsumsq);
    k_bnfin<<<1, 128, 0, stream>>>(fsum, fsumsq, gamma, beta, scale, shift);
    k_apply<<<(NN * OF / 4 + 255) / 256, 256, 0, stream>>>(out, scale, shift);
}

// Round 7
// 257.961 us; speedup vs baseline: 2.7567x; 1.0555x over previous
//
#include <hip/hip_runtime.h>
#include <hip/hip_fp16.h>
#include <math.h>

#define NN 50000
#define EE 800000
#define EP (EE + NN)          // 850000 edges incl self-loops
#define INF_ 256
#define OF 128
#define NEG_SLOPE 0.2f
#define BN_EPS 1e-5f
#define NB 196                // ceil(NN/256)
#define NWIN 8                // dst windows (XCD-aligned via blockIdx&7)
#define DPW 6250              // dsts per window
#define NTEAM 104             // blocks per window -> grid 832

typedef _Float16 half8 __attribute__((ext_vector_type(8)));
typedef float floatx4 __attribute__((ext_vector_type(4)));

// ---------------- GEMM (MFMA fp16): h = x @ W, plus a_src/a_dst dots ----------------
__global__ __launch_bounds__(256) void k_gemm(
    const float* __restrict__ x, const float* __restrict__ W,
    const float* __restrict__ att_s, const float* __restrict__ att_d,
    _Float16* __restrict__ h, float* __restrict__ a_src, float* __restrict__ a_dst)
{
    __shared__ __align__(16) _Float16 smem[64 * 72 + 128 * 72];  // 27648 B -> 5 blocks/CU
    _Float16* xh = smem;             // [64 rows][72] (k-major)
    _Float16* wh = smem + 64 * 72;   // [128 cols][72] (k-major, transposed W)

    const int tid  = threadIdx.x;
    const int l    = tid & 63;
    const int w    = tid >> 6;           // wave 0..3
    const int row0 = blockIdx.x * 64;
    const int lrow = l & 15;             // frag row (A) / col (B) / col (D)
    const int lk8  = (l >> 4) << 3;      // frag k base

    floatx4 acc[8];
    #pragma unroll
    for (int t = 0; t < 8; ++t) acc[t] = (floatx4){0.f, 0.f, 0.f, 0.f};

    for (int kc = 0; kc < 4; ++kc) {
        __syncthreads();
        #pragma unroll
        for (int it = 0; it < 4; ++it) {
            int i  = tid + (it << 8);
            int r  = i >> 4;
            int c4 = (i & 15) << 2;
            int rr = row0 + r; if (rr >= NN) rr = NN - 1;
            float4 v = *(const float4*)&x[rr * INF_ + (kc << 6) + c4];
            _Float16* p = &xh[r * 72 + c4];
            p[0] = (_Float16)v.x; p[1] = (_Float16)v.y;
            p[2] = (_Float16)v.z; p[3] = (_Float16)v.w;
        }
        #pragma unroll
        for (int it = 0; it < 8; ++it) {
            int i  = tid + (it << 8);    // 0..2047
            int k  = i >> 5;             // 0..63
            int c4 = (i & 31) << 2;      // 0..124
            float4 v = *(const float4*)&W[(kc * 64 + k) * OF + c4];
            wh[(c4 + 0) * 72 + k] = (_Float16)v.x;
            wh[(c4 + 1) * 72 + k] = (_Float16)v.y;
            wh[(c4 + 2) * 72 + k] = (_Float16)v.z;
            wh[(c4 + 3) * 72 + k] = (_Float16)v.w;
        }
        __syncthreads();
        #pragma unroll
        for (int ks = 0; ks < 2; ++ks) {
            half8 a = *(half8*)&xh[(w * 16 + lrow) * 72 + (ks << 5) + lk8];
            #pragma unroll
            for (int t = 0; t < 8; ++t) {
                half8 b = *(half8*)&wh[(t * 16 + lrow) * 72 + (ks << 5) + lk8];
                acc[t] = __builtin_amdgcn_mfma_f32_16x16x32_f16(a, b, acc[t], 0, 0, 0);
            }
        }
    }

    // ---- attention dots straight from accumulator fragments ----
    float as_c[8], ad_c[8];
    #pragma unroll
    for (int t = 0; t < 8; ++t) { as_c[t] = att_s[t * 16 + lrow]; ad_c[t] = att_d[t * 16 + lrow]; }
    float my_s = 0.f, my_d = 0.f;
    #pragma unroll
    for (int hh = 0; hh < 4; ++hh) {
        #pragma unroll
        for (int reg = 0; reg < 4; ++reg) {
            float ps = acc[2*hh][reg] * as_c[2*hh] + acc[2*hh+1][reg] * as_c[2*hh+1];
            float pd = acc[2*hh][reg] * ad_c[2*hh] + acc[2*hh+1][reg] * ad_c[2*hh+1];
            ps += __shfl_xor(ps, 1); ps += __shfl_xor(ps, 2); ps += __shfl_xor(ps, 4); ps += __shfl_xor(ps, 8);
            pd += __shfl_xor(pd, 1); pd += __shfl_xor(pd, 2); pd += __shfl_xor(pd, 4); pd += __shfl_xor(pd, 8);
            if (lrow == hh * 4 + reg) { my_s = ps; my_d = pd; }
        }
    }
    {
        int myreg = lrow & 3, myhh = lrow >> 2;
        int myrow = row0 + w * 16 + ((l >> 4) << 2) + myreg;
        if (myrow < NN) { a_src[myrow * 4 + myhh] = my_s; a_dst[myrow * 4 + myhh] = my_d; }
    }

    // ---- repack D through LDS, coalesced fp16 h stores ----
    __syncthreads();
    _Float16* ldso = smem + w * 2048;
    #pragma unroll
    for (int t = 0; t < 8; ++t)
        #pragma unroll
        for (int reg = 0; reg < 4; ++reg)
            ldso[(((l >> 4) << 2) + reg) * 128 + t * 16 + lrow] = (_Float16)acc[t][reg];
    __syncthreads();
    {
        _Float16* gdst = h + (size_t)(row0 + w * 16) * OF;
        #pragma unroll
        for (int q = 0; q < 4; ++q) {
            int off = (q << 9) + (l << 3);
            *(half8*)&gdst[off] = *(half8*)&ldso[off];
        }
    }
}

// ---------------- degree counts over real edges only ----------------
__global__ __launch_bounds__(256) void k_count(const int* __restrict__ ei, int* __restrict__ counts)
{
    int idx = blockIdx.x * 256 + threadIdx.x;
    if (idx >= EE) return;
    atomicAdd(&counts[ei[EE + idx]], 1);
}

// ---------------- hierarchical scan, stage 1: per-block sums ----------------
__global__ __launch_bounds__(256) void k_blocksum(const int* __restrict__ counts, int* __restrict__ partials)
{
    int i = blockIdx.x * 256 + threadIdx.x;
    int v = (i < NN) ? counts[i] + 1 : 0;
    v += __shfl_xor(v, 1);  v += __shfl_xor(v, 2);  v += __shfl_xor(v, 4);
    v += __shfl_xor(v, 8);  v += __shfl_xor(v, 16); v += __shfl_xor(v, 32);
    __shared__ int wsum[4];
    if ((threadIdx.x & 63) == 0) wsum[threadIdx.x >> 6] = v;
    __syncthreads();
    if (threadIdx.x == 0) partials[blockIdx.x] = wsum[0] + wsum[1] + wsum[2] + wsum[3];
}

// ---------------- stage 2: scan the 196 partials ----------------
__global__ __launch_bounds__(256) void k_scanpart(int* __restrict__ partials)
{
    __shared__ int sm[256];
    int t = threadIdx.x;
    int v = (t < NB) ? partials[t] : 0;
    sm[t] = v;
    __syncthreads();
    for (int off = 1; off < 256; off <<= 1) {
        int u = (t >= off) ? sm[t - off] : 0;
        __syncthreads();
        sm[t] += u;
        __syncthreads();
    }
    if (t < NB) partials[t] = sm[t] - v;   // exclusive
}

// ---------------- stage 3: per-block scan + offset -> row_start / fill_pos ----------------
__global__ __launch_bounds__(256) void k_writerows(
    const int* __restrict__ counts, const int* __restrict__ partials,
    int* __restrict__ row_start, int* __restrict__ fill_pos)
{
    __shared__ int sm[256];
    int t = threadIdx.x;
    int i = blockIdx.x * 256 + t;
    int v = (i < NN) ? counts[i] + 1 : 0;
    sm[t] = v;
    __syncthreads();
    for (int off = 1; off < 256; off <<= 1) {
        int u = (t >= off) ? sm[t - off] : 0;
        __syncthreads();
        sm[t] += u;
        __syncthreads();
    }
    int excl = partials[blockIdx.x] + sm[t] - v;
    if (i < NN) { row_start[i] = excl; fill_pos[i] = excl; }
    if (i == NN) row_start[NN] = excl;
}

// ---------------- windowed CSR fill: 8 dst-windows, team of NTEAM blocks each ----------------
// blockIdx&7 = window (XCD-aligned by round-robin dispatch heuristic; correctness
// independent of mapping). Each team sweeps all edges, handles only its window ->
// scattered csr_src writes stay within a 425KB L2-resident region, lines fill up
// before writeback (kills the 16x write amplification).
__global__ __launch_bounds__(256) void k_fillwin(
    const int* __restrict__ ei, int* __restrict__ fill_pos, int* __restrict__ csr_src)
{
    const int win  = blockIdx.x & 7;
    const int dlo  = win * DPW;
    const int dhi  = dlo + DPW;            // last window covers to 50000 exactly
    const int base = (blockIdx.x >> 3) * 256 + threadIdx.x;
    const int stride = NTEAM * 256;
    for (int idx = base; idx < EP; idx += stride) {
        int d = (idx < EE) ? ei[EE + idx] : idx - EE;
        if (d >= dlo && d < dhi) {
            int s = (idx < EE) ? ei[idx] : idx - EE;
            int pos = atomicAdd(&fill_pos[d], 1);
            csr_src[pos] = s;
        }
    }
}

// ---------------- per-(node,head) softmax: no atomics ----------------
__global__ __launch_bounds__(256) void k_alpha(
    const int* __restrict__ csr_src, const int* __restrict__ row_start,
    const float* __restrict__ a_src, const float* __restrict__ a_dst,
    float* __restrict__ csr_alpha, float* __restrict__ inv_denom)
{
    int gid = blockIdx.x * 256 + threadIdx.x;
    if (gid >= NN * 4) return;
    int node = gid >> 2;
    int hh   = gid & 3;
    int b = row_start[node];
    int e = row_start[node + 1];
    float ad = a_dst[node * 4 + hh];
    float m = -INFINITY;
    for (int k = b; k < e; ++k) {
        int s = csr_src[k];
        float v = a_src[s * 4 + hh] + ad;
        v = v > 0.f ? v : NEG_SLOPE * v;
        csr_alpha[(k << 2) + hh] = v;
        m = fmaxf(m, v);
    }
    float sum = 0.f;
    for (int k = b; k < e; ++k) {
        float v = csr_alpha[(k << 2) + hh];
        float xv = expf(v - m);
        sum += xv;
        csr_alpha[(k << 2) + hh] = xv;
    }
    inv_denom[gid] = 1.0f / (sum + 1e-16f);
}

// ---------------- gather: one wave per dst node, lane owns 2 cols (fp16 h), 4-edge unroll ----------------
__global__ __launch_bounds__(256) void k_gather(
    const __half* __restrict__ h, const int* __restrict__ csr_src,
    const float* __restrict__ csr_alpha, const int* __restrict__ row_start,
    const float* __restrict__ inv_denom, const float* __restrict__ bias,
    float* __restrict__ out)
{
    int node = blockIdx.x * 4 + (threadIdx.x >> 6);
    int lane = threadIdx.x & 63;
    int col  = lane << 1;
    int head = lane >> 4;
    int b = row_start[node];
    int e = row_start[node + 1];
    float ax = 0.f, ay = 0.f;
    int k = b;
    for (; k + 3 < e; k += 4) {
        int s0 = csr_src[k];
        int s1 = csr_src[k + 1];
        int s2 = csr_src[k + 2];
        int s3 = csr_src[k + 3];
        float a0 = csr_alpha[(k << 2) + head];
        float a1 = csr_alpha[((k + 1) << 2) + head];
        float a2 = csr_alpha[((k + 2) << 2) + head];
        float a3 = csr_alpha[((k + 3) << 2) + head];
        float2 h0 = __half22float2(*(const __half2*)&h[s0 * OF + col]);
        float2 h1 = __half22float2(*(const __half2*)&h[s1 * OF + col]);
        float2 h2 = __half22float2(*(const __half2*)&h[s2 * OF + col]);
        float2 h3 = __half22float2(*(const __half2*)&h[s3 * OF + col]);
        ax = fmaf(a0, h0.x, ax); ay = fmaf(a0, h0.y, ay);
        ax = fmaf(a1, h1.x, ax); ay = fmaf(a1, h1.y, ay);
        ax = fmaf(a2, h2.x, ax); ay = fmaf(a2, h2.y, ay);
        ax = fmaf(a3, h3.x, ax); ay = fmaf(a3, h3.y, ay);
    }
    for (; k < e; ++k) {
        int s0 = csr_src[k];
        float a0 = csr_alpha[(k << 2) + head];
        float2 h0 = __half22float2(*(const __half2*)&h[s0 * OF + col]);
        ax = fmaf(a0, h0.x, ax); ay = fmaf(a0, h0.y, ay);
    }
    float inv = inv_denom[(node << 2) + head];
    float2 bs = *(const float2*)&bias[col];
    *(float2*)&out[node * OF + col] = make_float2(fmaf(ax, inv, bs.x), fmaf(ay, inv, bs.y));
}

// ---------------- BN: per-feature sum / sumsq reduction ----------------
__global__ __launch_bounds__(256) void k_bnred(
    const float* __restrict__ out, float* __restrict__ fsum, float* __restrict__ fsumsq)
{
    int f = threadIdx.x & 127;
    int r = blockIdx.x * 2 + (threadIdx.x >> 7);
    float s = 0.f, ss = 0.f;
    for (; r < NN; r += gridDim.x * 2) {
        float v = out[r * OF + f];
        s += v;
        ss = fmaf(v, v, ss);
    }
    atomicAdd(&fsum[f], s);
    atomicAdd(&fsumsq[f], ss);
}

__global__ void k_bnfin(
    const float* __restrict__ fsum, const float* __restrict__ fsumsq,
    const float* __restrict__ gamma, const float* __restrict__ beta,
    float* __restrict__ scale, float* __restrict__ shift)
{
    int f = threadIdx.x;  // 128 threads
    float mean = fsum[f] * (1.0f / NN);
    float var  = fsumsq[f] * (1.0f / NN) - mean * mean;
    float sc   = gamma[f] * rsqrtf(var + BN_EPS);
    scale[f] = sc;
    shift[f] = beta[f] - mean * sc;
}

// ---------------- fused BN apply + ELU ----------------
__global__ __launch_bounds__(256) void k_apply(
    float* __restrict__ out, const float* __restrict__ scale, const float* __restrict__ shift)
{
    int i    = blockIdx.x * 256 + threadIdx.x;
    int base = i << 2;
    int f    = base & 127;
    float4 v  = *(float4*)&out[base];
    float4 sc = *(const float4*)&scale[f];
    float4 sh = *(const float4*)&shift[f];
    float r0 = fmaf(v.x, sc.x, sh.x); r0 = r0 > 0.f ? r0 : expm1f(r0);
    float r1 = fmaf(v.y, sc.y, sh.y); r1 = r1 > 0.f ? r1 : expm1f(r1);
    float r2 = fmaf(v.z, sc.z, sh.z); r2 = r2 > 0.f ? r2 : expm1f(r2);
    float r3 = fmaf(v.w, sc.w, sh.w); r3 = r3 > 0.f ? r3 : expm1f(r3);
    *(float4*)&out[base] = make_float4(r0, r1, r2, r3);
}

extern "C" void kernel_launch(void* const* d_in, const int* in_sizes, int n_in,
                              void* d_out, int out_size, void* d_ws, size_t ws_size,
                              hipStream_t stream)
{
    const float* x     = (const float*)d_in[0];
    const int*   ei    = (const int*)d_in[1];
    const float* W     = (const float*)d_in[2];
    const float* att_s = (const float*)d_in[3];
    const float* att_d = (const float*)d_in[4];
    const float* bias  = (const float*)d_in[5];
    const float* gamma = (const float*)d_in[6];
    const float* beta  = (const float*)d_in[7];
    float* out = (float*)d_out;

    float* ws        = (float*)d_ws;
    _Float16* h      = (_Float16*)ws;            // 50048*128 halves in 6.4M-float slot
    float* a_src     = ws + 6400000;             //   200,000
    float* a_dst     = a_src + 200000;           //   200,000
    float* csr_alpha = a_dst + 200000;           // 3,400,000
    float* inv_denom = csr_alpha + 3400000;      //   200,000
    float* fsum      = inv_denom + 200000;       //       128
    float* fsumsq    = fsum + 128;               //       128
    float* scale     = fsumsq + 128;             //       128
    float* shift     = scale + 128;              //       128
    int* counts      = (int*)(shift + 128);      //    50,000
    int* row_start   = counts + NN;              //    50,001
    int* fill_pos    = row_start + NN + 1;       //    50,000
    int* csr_src     = fill_pos + NN;            //   850,000
    int* partials    = csr_src + EP;             //       256

    hipMemsetAsync(counts, 0, NN * sizeof(int), stream);
    hipMemsetAsync(fsum, 0, 256 * sizeof(float), stream);        // fsum + fsumsq contiguous

    k_gemm<<<(NN + 63) / 64, 256, 0, stream>>>(x, W, att_s, att_d, h, a_src, a_dst);
    k_count<<<(EE + 255) / 256, 256, 0, stream>>>(ei, counts);
    k_blocksum<<<NB, 256, 0, stream>>>(counts, partials);
    k_scanpart<<<1, 256, 0, stream>>>(partials);
    k_writerows<<<NB, 256, 0, stream>>>(counts, partials, row_start, fill_pos);
    k_fillwin<<<NWIN * NTEAM, 256, 0, stream>>>(ei, fill_pos, csr_src);
    k_alpha<<<(NN * 4 + 255) / 256, 256, 0, stream>>>(csr_src, row_start, a_src, a_dst, csr_alpha, inv_denom);
    k_gather<<<NN / 4, 256, 0, stream>>>((const __half*)h, csr_src, csr_alpha, row_start, inv_denom, bias, out);
    k_bnred<<<512, 256, 0, stream>>>(out, fsum, fsumsq);
    k_bnfin<<<1, 128, 0, stream>>>(fsum, fsumsq, gamma, beta, scale, shift);
    k_apply<<<(NN * OF / 4 + 255) / 256, 256, 0, stream>>>(out, scale, shift);
}

// Round 8
// 237.411 us; speedup vs baseline: 2.9953x; 1.0866x over previous
//
#include <hip/hip_runtime.h>
#include <hip/hip_fp16.h>
#include <math.h>

#define NN 50000
#define EE 800000
#define EP (EE + NN)          // 850000 edges incl self-loops
#define INF_ 256
#define OF 128
#define NEG_SLOPE 0.2f
#define BN_EPS 1e-5f
#define NB 196                // ceil(NN/256)
#define NWIN 8                // dst windows
#define DPW 6250              // dsts per window
#define NTEAM 104             // blocks per window -> grid 832

typedef _Float16 half8 __attribute__((ext_vector_type(8)));
typedef float floatx4 __attribute__((ext_vector_type(4)));

// ---------------- W fragment prep: wfrag[((ksg*8+t)*64+l)*8+j] = W[ksg*32+((l>>4)<<3)+j][t*16+(l&15)] ----------------
// One-time 32768-half (64KB) stream in MFMA B-fragment order; L2-resident, reused by all gemm blocks.
__global__ __launch_bounds__(256) void k_wprep(const float* __restrict__ W, _Float16* __restrict__ wfrag)
{
    int idx = blockIdx.x * 256 + threadIdx.x;      // 0..32767
    int j   = idx & 7;
    int l   = (idx >> 3) & 63;
    int t   = (idx >> 9) & 7;
    int ksg = idx >> 12;
    int k   = ksg * 32 + ((l >> 4) << 3) + j;
    int col = t * 16 + (l & 15);
    wfrag[idx] = (_Float16)W[k * OF + col];
}

// ---------------- GEMM (MFMA fp16): h = x @ W, plus a_src/a_dst dots ----------------
// 64 rows x 128 cols per block, 4 waves; wave w owns rows [w*16,w*16+16) = 8 tiles 16x16x32.
// x staged in LDS (fp16, stride 72); B fragments loaded per-lane from global wfrag (L2-hot,
// static addresses, coalesced 1KB/instr) -- no LDS transpose, no bank conflicts.
__global__ __launch_bounds__(256) void k_gemm(
    const float* __restrict__ x, const _Float16* __restrict__ wfrag,
    const float* __restrict__ att_s, const float* __restrict__ att_d,
    _Float16* __restrict__ h, float* __restrict__ a_src, float* __restrict__ a_dst)
{
    __shared__ __align__(16) _Float16 smem[8192];   // 16KB: xh (64*72=4608) then reused for D repack
    _Float16* xh = smem;

    const int tid  = threadIdx.x;
    const int l    = tid & 63;
    const int w    = tid >> 6;           // wave 0..3
    const int row0 = blockIdx.x * 64;
    const int lrow = l & 15;             // frag row (A) / col (B) / col (D)
    const int lk8  = (l >> 4) << 3;      // frag k base

    floatx4 acc[8];
    #pragma unroll
    for (int t = 0; t < 8; ++t) acc[t] = (floatx4){0.f, 0.f, 0.f, 0.f};

    for (int kc = 0; kc < 4; ++kc) {
        __syncthreads();
        // stage x chunk: 64 rows x 64 k, f32 -> fp16
        #pragma unroll
        for (int it = 0; it < 4; ++it) {
            int i  = tid + (it << 8);
            int r  = i >> 4;
            int c4 = (i & 15) << 2;
            int rr = row0 + r; if (rr >= NN) rr = NN - 1;
            float4 v = *(const float4*)&x[rr * INF_ + (kc << 6) + c4];
            _Float16* p = &xh[r * 72 + c4];
            p[0] = (_Float16)v.x; p[1] = (_Float16)v.y;
            p[2] = (_Float16)v.z; p[3] = (_Float16)v.w;
        }
        __syncthreads();
        #pragma unroll
        for (int ks = 0; ks < 2; ++ks) {
            int ksg = kc * 2 + ks;
            half8 a = *(half8*)&xh[(w * 16 + lrow) * 72 + (ks << 5) + lk8];
            const _Float16* wf = &wfrag[(ksg << 12) + (l << 3)];
            #pragma unroll
            for (int t = 0; t < 8; ++t) {
                half8 b = *(const half8*)&wf[t << 9];
                acc[t] = __builtin_amdgcn_mfma_f32_16x16x32_f16(a, b, acc[t], 0, 0, 0);
            }
        }
    }

    // ---- attention dots straight from accumulator fragments ----
    float as_c[8], ad_c[8];
    #pragma unroll
    for (int t = 0; t < 8; ++t) { as_c[t] = att_s[t * 16 + lrow]; ad_c[t] = att_d[t * 16 + lrow]; }
    float my_s = 0.f, my_d = 0.f;
    #pragma unroll
    for (int hh = 0; hh < 4; ++hh) {
        #pragma unroll
        for (int reg = 0; reg < 4; ++reg) {
            float ps = acc[2*hh][reg] * as_c[2*hh] + acc[2*hh+1][reg] * as_c[2*hh+1];
            float pd = acc[2*hh][reg] * ad_c[2*hh] + acc[2*hh+1][reg] * ad_c[2*hh+1];
            ps += __shfl_xor(ps, 1); ps += __shfl_xor(ps, 2); ps += __shfl_xor(ps, 4); ps += __shfl_xor(ps, 8);
            pd += __shfl_xor(pd, 1); pd += __shfl_xor(pd, 2); pd += __shfl_xor(pd, 4); pd += __shfl_xor(pd, 8);
            if (lrow == hh * 4 + reg) { my_s = ps; my_d = pd; }
        }
    }
    {
        int myreg = lrow & 3, myhh = lrow >> 2;
        int myrow = row0 + w * 16 + ((l >> 4) << 2) + myreg;
        if (myrow < NN) { a_src[myrow * 4 + myhh] = my_s; a_dst[myrow * 4 + myhh] = my_d; }
    }

    // ---- repack D through LDS, coalesced fp16 h stores ----
    __syncthreads();
    _Float16* ldso = smem + w * 2048;
    #pragma unroll
    for (int t = 0; t < 8; ++t)
        #pragma unroll
        for (int reg = 0; reg < 4; ++reg)
            ldso[(((l >> 4) << 2) + reg) * 128 + t * 16 + lrow] = (_Float16)acc[t][reg];
    __syncthreads();
    {
        _Float16* gdst = h + (size_t)(row0 + w * 16) * OF;
        #pragma unroll
        for (int q = 0; q < 4; ++q) {
            int off = (q << 9) + (l << 3);
            *(half8*)&gdst[off] = *(half8*)&ldso[off];
        }
    }
}

// ---------------- degree counts over real edges only ----------------
__global__ __launch_bounds__(256) void k_count(const int* __restrict__ ei, int* __restrict__ counts)
{
    int idx = blockIdx.x * 256 + threadIdx.x;
    if (idx >= EE) return;
    atomicAdd(&counts[ei[EE + idx]], 1);
}

// ---------------- hierarchical scan, stage 1: per-block sums ----------------
__global__ __launch_bounds__(256) void k_blocksum(const int* __restrict__ counts, int* __restrict__ partials)
{
    int i = blockIdx.x * 256 + threadIdx.x;
    int v = (i < NN) ? counts[i] + 1 : 0;
    v += __shfl_xor(v, 1);  v += __shfl_xor(v, 2);  v += __shfl_xor(v, 4);
    v += __shfl_xor(v, 8);  v += __shfl_xor(v, 16); v += __shfl_xor(v, 32);
    __shared__ int wsum[4];
    if ((threadIdx.x & 63) == 0) wsum[threadIdx.x >> 6] = v;
    __syncthreads();
    if (threadIdx.x == 0) partials[blockIdx.x] = wsum[0] + wsum[1] + wsum[2] + wsum[3];
}

// ---------------- stage 2: scan the 196 partials ----------------
__global__ __launch_bounds__(256) void k_scanpart(int* __restrict__ partials)
{
    __shared__ int sm[256];
    int t = threadIdx.x;
    int v = (t < NB) ? partials[t] : 0;
    sm[t] = v;
    __syncthreads();
    for (int off = 1; off < 256; off <<= 1) {
        int u = (t >= off) ? sm[t - off] : 0;
        __syncthreads();
        sm[t] += u;
        __syncthreads();
    }
    if (t < NB) partials[t] = sm[t] - v;   // exclusive
}

// ---------------- stage 3: per-block scan + offset -> row_start / fill_pos ----------------
__global__ __launch_bounds__(256) void k_writerows(
    const int* __restrict__ counts, const int* __restrict__ partials,
    int* __restrict__ row_start, int* __restrict__ fill_pos)
{
    __shared__ int sm[256];
    int t = threadIdx.x;
    int i = blockIdx.x * 256 + t;
    int v = (i < NN) ? counts[i] + 1 : 0;
    sm[t] = v;
    __syncthreads();
    for (int off = 1; off < 256; off <<= 1) {
        int u = (t >= off) ? sm[t - off] : 0;
        __syncthreads();
        sm[t] += u;
        __syncthreads();
    }
    int excl = partials[blockIdx.x] + sm[t] - v;
    if (i < NN) { row_start[i] = excl; fill_pos[i] = excl; }
    if (i == NN) row_start[NN] = excl;
}

// ---------------- windowed CSR fill ----------------
__global__ __launch_bounds__(256) void k_fillwin(
    const int* __restrict__ ei, int* __restrict__ fill_pos, int* __restrict__ csr_src)
{
    const int win  = blockIdx.x & 7;
    const int dlo  = win * DPW;
    const int dhi  = dlo + DPW;
    const int base = (blockIdx.x >> 3) * 256 + threadIdx.x;
    const int stride = NTEAM * 256;
    for (int idx = base; idx < EP; idx += stride) {
        int d = (idx < EE) ? ei[EE + idx] : idx - EE;
        if (d >= dlo && d < dhi) {
            int s = (idx < EE) ? ei[idx] : idx - EE;
            int pos = atomicAdd(&fill_pos[d], 1);
            csr_src[pos] = s;
        }
    }
}

// ---------------- per-(node,head) softmax: no atomics ----------------
__global__ __launch_bounds__(256) void k_alpha(
    const int* __restrict__ csr_src, const int* __restrict__ row_start,
    const float* __restrict__ a_src, const float* __restrict__ a_dst,
    float* __restrict__ csr_alpha, float* __restrict__ inv_denom)
{
    int gid = blockIdx.x * 256 + threadIdx.x;
    if (gid >= NN * 4) return;
    int node = gid >> 2;
    int hh   = gid & 3;
    int b = row_start[node];
    int e = row_start[node + 1];
    float ad = a_dst[node * 4 + hh];
    float m = -INFINITY;
    for (int k = b; k < e; ++k) {
        int s = csr_src[k];
        float v = a_src[s * 4 + hh] + ad;
        v = v > 0.f ? v : NEG_SLOPE * v;
        csr_alpha[(k << 2) + hh] = v;
        m = fmaxf(m, v);
    }
    float sum = 0.f;
    for (int k = b; k < e; ++k) {
        float v = csr_alpha[(k << 2) + hh];
        float xv = expf(v - m);
        sum += xv;
        csr_alpha[(k << 2) + hh] = xv;
    }
    inv_denom[gid] = 1.0f / (sum + 1e-16f);
}

// ---------------- gather: one wave per dst node, lane owns 2 cols (fp16 h), 4-edge unroll ----------------
__global__ __launch_bounds__(256) void k_gather(
    const __half* __restrict__ h, const int* __restrict__ csr_src,
    const float* __restrict__ csr_alpha, const int* __restrict__ row_start,
    const float* __restrict__ inv_denom, const float* __restrict__ bias,
    float* __restrict__ out)
{
    int node = blockIdx.x * 4 + (threadIdx.x >> 6);
    int lane = threadIdx.x & 63;
    int col  = lane << 1;
    int head = lane >> 4;
    int b = row_start[node];
    int e = row_start[node + 1];
    float ax = 0.f, ay = 0.f;
    int k = b;
    for (; k + 3 < e; k += 4) {
        int s0 = csr_src[k];
        int s1 = csr_src[k + 1];
        int s2 = csr_src[k + 2];
        int s3 = csr_src[k + 3];
        float a0 = csr_alpha[(k << 2) + head];
        float a1 = csr_alpha[((k + 1) << 2) + head];
        float a2 = csr_alpha[((k + 2) << 2) + head];
        float a3 = csr_alpha[((k + 3) << 2) + head];
        float2 h0 = __half22float2(*(const __half2*)&h[s0 * OF + col]);
        float2 h1 = __half22float2(*(const __half2*)&h[s1 * OF + col]);
        float2 h2 = __half22float2(*(const __half2*)&h[s2 * OF + col]);
        float2 h3 = __half22float2(*(const __half2*)&h[s3 * OF + col]);
        ax = fmaf(a0, h0.x, ax); ay = fmaf(a0, h0.y, ay);
        ax = fmaf(a1, h1.x, ax); ay = fmaf(a1, h1.y, ay);
        ax = fmaf(a2, h2.x, ax); ay = fmaf(a2, h2.y, ay);
        ax = fmaf(a3, h3.x, ax); ay = fmaf(a3, h3.y, ay);
    }
    for (; k < e; ++k) {
        int s0 = csr_src[k];
        float a0 = csr_alpha[(k << 2) + head];
        float2 h0 = __half22float2(*(const __half2*)&h[s0 * OF + col]);
        ax = fmaf(a0, h0.x, ax); ay = fmaf(a0, h0.y, ay);
    }
    float inv = inv_denom[(node << 2) + head];
    float2 bs = *(const float2*)&bias[col];
    *(float2*)&out[node * OF + col] = make_float2(fmaf(ax, inv, bs.x), fmaf(ay, inv, bs.y));
}

// ---------------- BN: per-feature sum / sumsq reduction ----------------
__global__ __launch_bounds__(256) void k_bnred(
    const float* __restrict__ out, float* __restrict__ fsum, float* __restrict__ fsumsq)
{
    int f = threadIdx.x & 127;
    int r = blockIdx.x * 2 + (threadIdx.x >> 7);
    float s = 0.f, ss = 0.f;
    for (; r < NN; r += gridDim.x * 2) {
        float v = out[r * OF + f];
        s += v;
        ss = fmaf(v, v, ss);
    }
    atomicAdd(&fsum[f], s);
    atomicAdd(&fsumsq[f], ss);
}

__global__ void k_bnfin(
    const float* __restrict__ fsum, const float* __restrict__ fsumsq,
    const float* __restrict__ gamma, const float* __restrict__ beta,
    float* __restrict__ scale, float* __restrict__ shift)
{
    int f = threadIdx.x;  // 128 threads
    float mean = fsum[f] * (1.0f / NN);
    float var  = fsumsq[f] * (1.0f / NN) - mean * mean;
    float sc   = gamma[f] * rsqrtf(var + BN_EPS);
    scale[f] = sc;
    shift[f] = beta[f] - mean * sc;
}

// ---------------- fused BN apply + ELU ----------------
__global__ __launch_bounds__(256) void k_apply(
    float* __restrict__ out, const float* __restrict__ scale, const float* __restrict__ shift)
{
    int i    = blockIdx.x * 256 + threadIdx.x;
    int base = i << 2;
    int f    = base & 127;
    float4 v  = *(float4*)&out[base];
    float4 sc = *(const float4*)&scale[f];
    float4 sh = *(const float4*)&shift[f];
    float r0 = fmaf(v.x, sc.x, sh.x); r0 = r0 > 0.f ? r0 : expm1f(r0);
    float r1 = fmaf(v.y, sc.y, sh.y); r1 = r1 > 0.f ? r1 : expm1f(r1);
    float r2 = fmaf(v.z, sc.z, sh.z); r2 = r2 > 0.f ? r2 : expm1f(r2);
    float r3 = fmaf(v.w, sc.w, sh.w); r3 = r3 > 0.f ? r3 : expm1f(r3);
    *(float4*)&out[base] = make_float4(r0, r1, r2, r3);
}

extern "C" void kernel_launch(void* const* d_in, const int* in_sizes, int n_in,
                              void* d_out, int out_size, void* d_ws, size_t ws_size,
                              hipStream_t stream)
{
    const float* x     = (const float*)d_in[0];
    const int*   ei    = (const int*)d_in[1];
    const float* W     = (const float*)d_in[2];
    const float* att_s = (const float*)d_in[3];
    const float* att_d = (const float*)d_in[4];
    const float* bias  = (const float*)d_in[5];
    const float* gamma = (const float*)d_in[6];
    const float* beta  = (const float*)d_in[7];
    float* out = (float*)d_out;

    float* ws        = (float*)d_ws;
    _Float16* h      = (_Float16*)ws;            // 50048*128 halves in 6.4M-float slot
    float* a_src     = ws + 6400000;             //   200,000
    float* a_dst     = a_src + 200000;           //   200,000
    float* csr_alpha = a_dst + 200000;           // 3,400,000 (k_alpha onward)
    float* inv_denom = csr_alpha + 3400000;      //   200,000
    float* fsum      = inv_denom + 200000;       //       128
    float* fsumsq    = fsum + 128;               //       128
    float* scale     = fsumsq + 128;             //       128
    float* shift     = scale + 128;              //       128
    int* counts      = (int*)(shift + 128);      //    50,000
    int* row_start   = counts + NN;              //    50,001
    int* fill_pos    = row_start + NN + 1;       //    50,000
    int* csr_src     = fill_pos + NN;            //   850,000
    int* partials    = csr_src + EP;             //       256
    _Float16* wfrag  = (_Float16*)csr_alpha;     // 32768 halves; dead before k_alpha writes

    hipMemsetAsync(counts, 0, NN * sizeof(int), stream);
    hipMemsetAsync(fsum, 0, 256 * sizeof(float), stream);        // fsum + fsumsq contiguous

    k_wprep<<<128, 256, 0, stream>>>(W, wfrag);
    k_gemm<<<(NN + 63) / 64, 256, 0, stream>>>(x, wfrag, att_s, att_d, h, a_src, a_dst);
    k_count<<<(EE + 255) / 256, 256, 0, stream>>>(ei, counts);
    k_blocksum<<<NB, 256, 0, stream>>>(counts, partials);
    k_scanpart<<<1, 256, 0, stream>>>(partials);
    k_writerows<<<NB, 256, 0, stream>>>(counts, partials, row_start, fill_pos);
    k_fillwin<<<NWIN * NTEAM, 256, 0, stream>>>(ei, fill_pos, csr_src);
    k_alpha<<<(NN * 4 + 255) / 256, 256, 0, stream>>>(csr_src, row_start, a_src, a_dst, csr_alpha, inv_denom);
    k_gather<<<NN / 4, 256, 0, stream>>>((const __half*)h, csr_src, csr_alpha, row_start, inv_denom, bias, out);
    k_bnred<<<512, 256, 0, stream>>>(out, fsum, fsumsq);
    k_bnfin<<<1, 128, 0, stream>>>(fsum, fsumsq, gamma, beta, scale, shift);
    k_apply<<<(NN * OF / 4 + 255) / 256, 256, 0, stream>>>(out, scale, shift);
}